// Round 20
// baseline (498.923 us; speedup 1.0000x reference)
//
#include <hip/hip_runtime.h>
#include <math.h>

#define B_ 32
#define S_ 50
#define H_ 256
#define T_ 25
#define V_ 50257
#define VP 50264    /* padded g_lgt row: 16B-aligned rows (6283 uint4 groups) */
#define NCH 786     /* 393 n-blocks x 2 wave-cols */
#define NROW (B_ * T_)
#define NWROW 1024  /* 256 Wa + 768 W_hh */
#define VT_ 3144    /* 393 * 8 vocab 16-col tiles */
#define MROW 54     /* padded M row (ushorts): 27 u32, gcd(27,32)=1 */
#define SOS 0

typedef unsigned short ushort_t;
typedef __attribute__((ext_vector_type(8))) unsigned short ushort8;
typedef __attribute__((ext_vector_type(8))) short short8v;
typedef __attribute__((ext_vector_type(4))) float f32x4;
typedef _Float16 half2v __attribute__((ext_vector_type(2)));

// ---- static device scratch (loader-allocated; fully rewritten each call)
__device__ ushort_t g_ua[B_ * S_ * H_];          // bf16 ua_keys + (Ua_b+Wa_b) folded
__device__ ushort_t g_hbf[NROW * H_];            // bf16 h2, row m = b*T+t
__device__ float    g_gie[T_ * B_ * 3 * H_];     // W_ih[:,:256].emb + b_ih
__device__ ushort_t g_wpk[(size_t)VT_ * 32 * 16 * 8];  // out_w bf16, fragment-major
__device__ ushort_t g_wcat[NWROW * H_];          // packed F16 [Wa; W_hh], K=256
__device__ ushort_t g_MT2[B_ * 768 * MROW];      // M[j][s] F16 padded rows
__device__ ushort_t g_lgt[(size_t)NROW * VP];    // bf16 logits staging (80 MB, padded)
__device__ float    g_psum[NROW * NCH];

__device__ __forceinline__ float bf2f(ushort_t h) {
  union { unsigned int u; float f; } c; c.u = ((unsigned int)h) << 16; return c.f;
}
__device__ __forceinline__ ushort_t f2bf(float f) {
  union { float f; unsigned int u; } c; c.f = f;
  unsigned int u = c.u;
  return (ushort_t)((u + 0x7FFFu + ((u >> 16) & 1u)) >> 16);
}
__device__ __forceinline__ ushort_t f2h(float f) {
  union { _Float16 h; ushort_t u; } c; c.h = (_Float16)f; return c.u;
}
__device__ __forceinline__ float dot2(unsigned int a, unsigned int b, float c) {
#if __has_builtin(__builtin_amdgcn_fdot2)
  union { unsigned int u; half2v h; } ca, cb;
  ca.u = a; cb.u = b;
  return __builtin_amdgcn_fdot2(ca.h, cb.h, c, false);
#else
  union { unsigned int u; _Float16 h[2]; } ca, cb;
  ca.u = a; cb.u = b;
  return c + (float)ca.h[0] * (float)cb.h[0] + (float)ca.h[1] * (float)cb.h[1];
#endif
}
__device__ __forceinline__ float tanh_fast(float x) {
  const float e = __expf(2.f * x);
  return 1.f - 2.f / (e + 1.f);
}

// ---------------- ONE setup launch, role by block range:
// [0,26): ua MFMA | [26,410): M | [410,710): gie | [710,966): wcat
__global__ void k_pre(const float* __restrict__ keys, const float* __restrict__ Ua_w,
                      const float* __restrict__ Ua_b, const float* __restrict__ Wa_b,
                      const float* __restrict__ W_hh, const float* __restrict__ Wa_w,
                      const float* __restrict__ W_ih, const float* __restrict__ b_ih,
                      const int* __restrict__ tgt, const float* __restrict__ emb_tab) {
  __shared__ float sbuf[16384];   // 64 KB, aliased per role
  const int bid = blockIdx.x, tid = threadIdx.x;

  if (bid < 26) {
    // ---- ua MFMA: ua[r=(b,s)][g] = keys_bf16[r,:] . Ua_w[g,:] + (Ua_b+Wa_b)[g]
    ushort_t* sA = (ushort_t*)sbuf;
    const int bx = bid & 1, by = bid >> 1;
    const int n0 = bx * 128, m0 = by * 128;
    const int lane = tid & 63, wv = tid >> 6;
    const int wm = wv >> 1, wn = wv & 1;
    const int l16 = lane & 15, l4 = lane >> 4;

    for (int i = tid; i < 128 * 32; i += 256) {
      const int row = i >> 5, ks = i & 31;
      const int m = m0 + row;
      ushort8 val = {0, 0, 0, 0, 0, 0, 0, 0};
      if (m < B_ * S_) {
        const float4* kr = (const float4*)(keys + (size_t)m * H_ + ks * 8);
        const float4 f0 = kr[0], f1 = kr[1];
        val[0] = f2bf(f0.x); val[1] = f2bf(f0.y); val[2] = f2bf(f0.z); val[3] = f2bf(f0.w);
        val[4] = f2bf(f1.x); val[5] = f2bf(f1.y); val[6] = f2bf(f1.z); val[7] = f2bf(f1.w);
      }
      *(ushort8*)((char*)sA + row * 512 + ((ks ^ (row & 7)) << 4)) = val;
    }
    __syncthreads();

    f32x4 acc[4][4];
#pragma unroll
    for (int mi = 0; mi < 4; ++mi)
#pragma unroll
      for (int ni = 0; ni < 4; ++ni) acc[mi][ni] = (f32x4){0.f, 0.f, 0.f, 0.f};

#pragma unroll 1
    for (int kk = 0; kk < 8; ++kk) {
      short8v a[4], bfr[4];
#pragma unroll
      for (int mi = 0; mi < 4; ++mi) {
        const int row = wm * 64 + mi * 16 + l16;
        const int ks = kk * 4 + l4;
        a[mi] = *(const short8v*)((const char*)sA + row * 512 + ((ks ^ (row & 7)) << 4));
      }
#pragma unroll
      for (int ni = 0; ni < 4; ++ni) {
        const int g = n0 + wn * 64 + ni * 16 + l16;
        const float4* wr = (const float4*)(Ua_w + (size_t)g * H_ + kk * 32 + l4 * 8);
        const float4 f0 = wr[0], f1 = wr[1];
        short8v bv;
        bv[0] = (short)f2bf(f0.x); bv[1] = (short)f2bf(f0.y);
        bv[2] = (short)f2bf(f0.z); bv[3] = (short)f2bf(f0.w);
        bv[4] = (short)f2bf(f1.x); bv[5] = (short)f2bf(f1.y);
        bv[6] = (short)f2bf(f1.z); bv[7] = (short)f2bf(f1.w);
        bfr[ni] = bv;
      }
#pragma unroll
      for (int mi = 0; mi < 4; ++mi)
#pragma unroll
        for (int ni = 0; ni < 4; ++ni)
          acc[mi][ni] = __builtin_amdgcn_mfma_f32_16x16x32_bf16(a[mi], bfr[ni], acc[mi][ni], 0, 0, 0);
    }

    int col[4]; float bias[4];
#pragma unroll
    for (int ni = 0; ni < 4; ++ni) {
      col[ni] = n0 + wn * 64 + ni * 16 + l16;
      bias[ni] = Ua_b[col[ni]] + Wa_b[col[ni]];
    }
#pragma unroll
    for (int mi = 0; mi < 4; ++mi) {
#pragma unroll
      for (int j = 0; j < 4; ++j) {
        const int m = m0 + wm * 64 + mi * 16 + l4 * 4 + j;
        if (m < B_ * S_) {
#pragma unroll
          for (int ni = 0; ni < 4; ++ni)
            g_ua[(size_t)m * H_ + col[ni]] = f2bf(acc[mi][ni][j] + bias[ni]);
        }
      }
    }
  } else if (bid < 410) {
    // ---- M[j][s] = W_ih[j,256:] . keys[b,s,:]  (F16 out)
    const int cc = bid - 26;
    const int c = cc % 12, b = cc / 12;
    {
      const float4* src = (const float4*)(keys + (size_t)b * S_ * H_);
      float4* dst = (float4*)sbuf;
      for (int i = tid; i < S_ * H_ / 4; i += 256) dst[i] = src[i];
    }
    __syncthreads();
    const int sub = tid & 15, grp = tid >> 4;
#pragma unroll 1
    for (int it = 0; it < 4; ++it) {
      const int j = c * 64 + it * 16 + grp;
      float w16[16];
#pragma unroll
      for (int kp = 0; kp < 16; ++kp)
        w16[kp] = W_ih[(size_t)j * (2 * H_) + H_ + sub + 16 * kp];
#pragma unroll 1
      for (int s = 0; s < S_; ++s) {
        float a = 0.f;
#pragma unroll
        for (int kp = 0; kp < 16; ++kp) a += w16[kp] * sbuf[s * H_ + sub + 16 * kp];
        a += __shfl_xor(a, 8); a += __shfl_xor(a, 4);
        a += __shfl_xor(a, 2); a += __shfl_xor(a, 1);
        if (sub == 0) g_MT2[(size_t)b * 768 * MROW + j * MROW + s] = f2h(a);
      }
    }
  } else if (bid < 710) {
    // ---- gie[t][b][j] = emb(tok[t,b]) . W_ih[j,:256] + b_ih[j]
    const int cc = bid - 410;
    const int chunk = cc % 12, t = cc / 12;
    for (int i = tid; i < B_ * H_; i += 256) {
      const int b = i >> 8, g = i & 255;
      const int tok = (t == 0) ? SOS : tgt[b * T_ + (t - 1)];
      sbuf[i] = emb_tab[(size_t)tok * H_ + g];
    }
    __syncthreads();
    const int vl = tid & 63, wd = tid >> 6;
    const int j = chunk * 64 + vl;
    const float4* wrow = (const float4*)(W_ih + (size_t)j * (2 * H_));
    const float4* se4 = (const float4*)sbuf;
    float acc[8];
    const float base = b_ih[j];
#pragma unroll
    for (int bb = 0; bb < 8; ++bb) acc[bb] = base;
    for (int k4 = 0; k4 < 64; ++k4) {
      const float4 w = wrow[k4];
#pragma unroll
      for (int bb = 0; bb < 8; ++bb) {
        const float4 x = se4[(wd * 8 + bb) * 64 + k4];
        acc[bb] += w.x * x.x + w.y * x.y + w.z * x.z + w.w * x.w;
      }
    }
#pragma unroll
    for (int bb = 0; bb < 8; ++bb)
      g_gie[((size_t)t * B_ + (wd * 8 + bb)) * (3 * H_) + j] = acc[bb];
  } else {
    // ---- wcat pack: [Wa; W_hh] -> F16
    const size_t i0 = (size_t)(bid - 710) * 256 + tid;
    for (size_t i = i0; i < (size_t)NWROW * H_; i += 256u * 256u) {
      const int r = (int)(i >> 8), k = (int)(i & 255);
      const float v = (r < 256) ? Wa_w[r * H_ + k] : W_hh[(r - 256) * H_ + k];
      g_wcat[i] = f2h(v);
    }
  }
}

// ---------------- recurrence (blocks 0..31) + g_wpk pack (blocks 32..) in ONE launch.
__global__ void __launch_bounds__(1024, 1)
k_recur(const float* __restrict__ enc_h, const float* __restrict__ Va_w,
        const float* __restrict__ Va_b, const float* __restrict__ b_hh,
        const float* __restrict__ out_w, float* __restrict__ out) {
  __shared__ ushort_t s_ua[S_ * H_];       // 25.6 KB bf16
  __shared__ ushort_t s_M[768 * MROW];     // 81 KB f16, [j][54]
  __shared__ float s_res[NWROW];           // 4 KB
  __shared__ float s_mw[768];              // 3 KB
  __shared__ ushort_t s_hh[H_];            // f16 h (dot2 operand)
  __shared__ ushort_t s_wh[64];            // f16 attention weights
  __shared__ float s_va[H_];
  __shared__ float s_score[64];
  const int bidx = blockIdx.x, tid = threadIdx.x;

  if (bidx >= 32) {
    // ---- pack out_w into fragment-major g_wpk (bf16): p = (vt*32 + kg)*16 + c
    const size_t total = (size_t)VT_ * 32 * 16;
    for (size_t p = (size_t)(bidx - 32) * 1024 + tid; p < total;
         p += (size_t)(gridDim.x - 32) * 1024) {
      const int c = (int)(p & 15);
      const int kg = (int)((p >> 4) & 31);
      const int vt = (int)(p >> 9);
      const int v = vt * 16 + c;
      short8v val = {0, 0, 0, 0, 0, 0, 0, 0};
      if (v < V_) {
        const float4* owr = (const float4*)(out_w + (size_t)v * H_ + kg * 8);
        const float4 f0 = owr[0], f1 = owr[1];
        val[0] = (short)f2bf(f0.x); val[1] = (short)f2bf(f0.y);
        val[2] = (short)f2bf(f0.z); val[3] = (short)f2bf(f0.w);
        val[4] = (short)f2bf(f1.x); val[5] = (short)f2bf(f1.y);
        val[6] = (short)f2bf(f1.z); val[7] = (short)f2bf(f1.w);
      }
      ((short8v*)g_wpk)[p] = val;
    }
    return;
  }

  const int b = bidx;
  const int lane = tid & 63, wid = tid >> 6;
  const int sub = lane & 15;
  const int grp = tid >> 4;            // 0..63 row-slot (16 lanes per row)

  {
    const uint4* src = (const uint4*)(g_ua + (size_t)b * S_ * H_);
    uint4* dst = (uint4*)s_ua;
    for (int i = tid; i < S_ * H_ / 8; i += 1024) dst[i] = src[i];
    const uint4* src2 = (const uint4*)(g_MT2 + (size_t)b * 768 * MROW);
    uint4* dst2 = (uint4*)s_M;
    for (int i = tid; i < 768 * MROW / 8; i += 1024) dst2[i] = src2[i];
  }
  float hreg = 0.f, bhh0 = 0.f, bhh1 = 0.f, bhh2 = 0.f;
  if (tid < H_) {
    hreg = enc_h[b * H_ + tid];
    s_hh[tid] = f2h(hreg);
    s_va[tid] = Va_w[tid];
    bhh0 = b_hh[tid]; bhh1 = b_hh[H_ + tid]; bhh2 = b_hh[2 * H_ + tid];
  }
  const float vab = Va_b[0];
  __syncthreads();

  for (int t = 0; t < T_; ++t) {
    float gie0 = 0.f, gie1 = 0.f, gie2 = 0.f;
    if (tid < H_) {
      const float* gp = g_gie + ((size_t)t * B_ + b) * (3 * H_);
      gie0 = gp[tid]; gie1 = gp[H_ + tid]; gie2 = gp[2 * H_ + tid];
    }

    // ---- phase A: coalesced f16-dot2 sweep s_res[0..1024) = g_wcat . h
    {
      const unsigned int* hh = (const unsigned int*)s_hh;
#pragma unroll 4
      for (int it = 0; it < 16; ++it) {
        const int row = it * 64 + grp;
        const uint4* wr = (const uint4*)(g_wcat + (size_t)row * H_);
        const uint4 w0 = wr[sub], w1 = wr[16 + sub];
        float a = 0.f;
        a = dot2(w0.x, hh[sub * 4 + 0], a);
        a = dot2(w0.y, hh[sub * 4 + 1], a);
        a = dot2(w0.z, hh[sub * 4 + 2], a);
        a = dot2(w0.w, hh[sub * 4 + 3], a);
        a = dot2(w1.x, hh[64 + sub * 4 + 0], a);
        a = dot2(w1.y, hh[64 + sub * 4 + 1], a);
        a = dot2(w1.z, hh[64 + sub * 4 + 2], a);
        a = dot2(w1.w, hh[64 + sub * 4 + 3], a);
        a += __shfl_xor(a, 8); a += __shfl_xor(a, 4);
        a += __shfl_xor(a, 2); a += __shfl_xor(a, 1);
        if (sub == 0) s_res[row] = a;
      }
    }
    __syncthreads();

    // ---- phase B: scores
    for (int s = wid; s < S_; s += 16) {
      const ushort_t* uarow = s_ua + s * H_;
      float acc = 0.f;
#pragma unroll
      for (int i = 0; i < 4; ++i) {
        const int gg = lane + i * 64;
        acc += tanh_fast(s_res[gg] + bf2f(uarow[gg])) * s_va[gg];
      }
      for (int off = 32; off > 0; off >>= 1) acc += __shfl_xor(acc, off);
      if (lane == 0) s_score[s] = acc + vab;
    }
    __syncthreads();

    // ---- phase C: softmax on wave 0; write attention output
    if (tid < 64) {
      const float v = (tid < S_) ? s_score[tid] : -INFINITY;
      float m = v;
      for (int off = 32; off > 0; off >>= 1) m = fmaxf(m, __shfl_xor(m, off));
      const float e = (tid < S_) ? __expf(v - m) : 0.f;
      float ssum = e;
      for (int off = 32; off > 0; off >>= 1) ssum += __shfl_xor(ssum, off);
      const float w = e / ssum;
      if (tid < S_) {
        s_wh[tid] = f2h(w);
        out[(size_t)B_ * T_ * V_ + (size_t)B_ * H_ + (size_t)(b * T_ + t) * S_ + tid] = w;
      }
    }
    __syncthreads();

    // ---- phase D1: 768 threads, f16-dot2 M.w (25 u32 pairs, conflict-free stride-27)
    if (tid < 768) {
      const unsigned int* m32 = (const unsigned int*)s_M + tid * (MROW / 2);
      const unsigned int* ww = (const unsigned int*)s_wh;
      float acc = 0.f;
#pragma unroll
      for (int i = 0; i < 25; ++i) acc = dot2(m32[i], ww[i], acc);
      s_mw[tid] = acc;
    }
    __syncthreads();

    // ---- phase D2: GRU finish + h update
    if (tid < H_) {
      const float gi0 = gie0 + s_mw[tid];
      const float gi1 = gie1 + s_mw[H_ + tid];
      const float gi2 = gie2 + s_mw[2 * H_ + tid];
      const float gh0 = s_res[256 + tid] + bhh0;
      const float gh1 = s_res[512 + tid] + bhh1;
      const float gh2 = s_res[768 + tid] + bhh2;
      const float r = 1.f / (1.f + __expf(-(gi0 + gh0)));
      const float z = 1.f / (1.f + __expf(-(gi1 + gh1)));
      const float n = tanh_fast(gi2 + r * gh2);
      const float h2 = (1.f - z) * n + z * hreg;
      hreg = h2;
      s_hh[tid] = f2h(h2);
      g_hbf[((size_t)b * T_ + t) * H_ + tid] = f2bf(h2);
      if (t == T_ - 1) out[(size_t)B_ * T_ * V_ + b * H_ + tid] = h2;
    }
    __syncthreads();
  }
}

// ---------------- MFMA logits GEMM, B staged in LDS once, loop all 7 m-tiles.
// Epilogue: fixed-max softmax partials (logits bounded ~|12| << f32 range).
__global__ void __launch_bounds__(512, 1)
k_logits(const float* __restrict__ out_b) {
  __shared__ ushort_t sA[128 * 256];   // 64 KB, XOR-swizzled rows
  __shared__ ushort_t sB[128 * 256];   // 64 KB, fragment-major copy of this block's B
  const int tid = threadIdx.x, nb = blockIdx.x;
  const int n0 = nb * 128;
  const int lane = tid & 63, wv = tid >> 6;
  const int wm = wv >> 1, wn = wv & 1;          // 4 x 2
  const int l16 = lane & 15, l4 = lane >> 4;

  // stage B once: 8 local vocab-16 tiles = 4096 short8v
  {
    const short8v* src = (const short8v*)g_wpk + (size_t)nb * 4096;
    short8v* dst = (short8v*)sB;
    for (int i = tid; i < 4096; i += 512) dst[i] = src[i];
  }

  int vcol[4]; float bias[4]; bool valid[4];
#pragma unroll
  for (int ni = 0; ni < 4; ++ni) {
    vcol[ni] = n0 + wn * 64 + ni * 16 + l16;
    valid[ni] = (vcol[ni] < V_);
    bias[ni] = valid[ni] ? out_b[vcol[ni]] : 0.f;
  }
  const int chunk = nb * 2 + wn;

#pragma unroll 1
  for (int mt = 0; mt < 7; ++mt) {
    const int m0 = mt * 128;
    __syncthreads();   // protect sA from previous iteration's readers; covers sB stage at mt=0
    for (int i = tid; i < 128 * 32; i += 512) {
      const int row = i >> 5, ks = i & 31;
      const int m = m0 + row;
      ushort8 val;
      if (m < NROW) val = ((const ushort8*)(g_hbf + (size_t)m * H_))[ks];
      else { ushort8 z = {0, 0, 0, 0, 0, 0, 0, 0}; val = z; }
      *(ushort8*)((char*)sA + row * 512 + ((ks ^ (row & 7)) << 4)) = val;
    }
    __syncthreads();

    f32x4 acc[2][4];
#pragma unroll
    for (int mi = 0; mi < 2; ++mi)
#pragma unroll
      for (int ni = 0; ni < 4; ++ni) acc[mi][ni] = (f32x4){0.f, 0.f, 0.f, 0.f};

#pragma unroll 1
    for (int kk = 0; kk < 8; ++kk) {
      short8v a[2], bfr[4];
#pragma unroll
      for (int mi = 0; mi < 2; ++mi) {
        const int row = wm * 32 + mi * 16 + l16;
        const int ks = kk * 4 + l4;
        a[mi] = *(const short8v*)((const char*)sA + row * 512 + ((ks ^ (row & 7)) << 4));
      }
#pragma unroll
      for (int ni = 0; ni < 4; ++ni)
        bfr[ni] = ((const short8v*)sB)[(((wn * 4 + ni) * 32) + kk * 4 + l4) * 16 + l16];
#pragma unroll
      for (int mi = 0; mi < 2; ++mi)
#pragma unroll
        for (int ni = 0; ni < 4; ++ni)
          acc[mi][ni] = __builtin_amdgcn_mfma_f32_16x16x32_bf16(a[mi], bfr[ni], acc[mi][ni], 0, 0, 0);
    }

#pragma unroll
    for (int mi = 0; mi < 2; ++mi) {
#pragma unroll
      for (int j = 0; j < 4; ++j) {
        const int m = m0 + wm * 32 + mi * 16 + l4 * 4 + j;
        float vv[4];
        float es = 0.f;
#pragma unroll
        for (int ni = 0; ni < 4; ++ni) {
          vv[ni] = acc[mi][ni][j] + bias[ni];
          if (valid[ni]) es += __expf(vv[ni]);
        }
        es += __shfl_xor(es, 1); es += __shfl_xor(es, 2);
        es += __shfl_xor(es, 4); es += __shfl_xor(es, 8);
        if (m < NROW) {
#pragma unroll
          for (int ni = 0; ni < 4; ++ni)
            if (valid[ni]) g_lgt[(size_t)m * VP + vcol[ni]] = f2bf(vv[ni]);
          if (l16 == 0) g_psum[(size_t)m * NCH + chunk] = es;
        }
      }
    }
  }
}

// ---------------- lse[r]=log(sum psum) + streamed write. grid (4, 800) x 256
__global__ void k_wlse(float* __restrict__ out) {
  __shared__ float red[4];
  const int r = blockIdx.y;
  const int tid = threadIdx.x;
  float s = 0.f;
  for (int i = tid; i < NCH; i += 256) s += g_psum[(size_t)r * NCH + i];
  for (int off = 32; off > 0; off >>= 1) s += __shfl_xor(s, off);
  if ((tid & 63) == 0) red[tid >> 6] = s;
  __syncthreads();
  s = red[0] + red[1] + red[2] + red[3];
  float lse = logf(s);
  if (!isfinite(lse)) lse = 0.f;
  const size_t obase = (size_t)r * V_;
  const uint4* row16 = (const uint4*)(g_lgt + (size_t)r * VP);
  const int g0 = blockIdx.x * 1571;
  const int g1 = (g0 + 1571 < 6283) ? g0 + 1571 : 6283;  // 6283 uint4 groups/row
#pragma unroll 2
  for (int g = g0 + tid; g < g1; g += 256) {
    const uint4 u = row16[g];
    const int v0 = g * 8;
    float vals[8];
    vals[0] = bf2f((ushort_t)(u.x & 0xffffu)); vals[1] = bf2f((ushort_t)(u.x >> 16));
    vals[2] = bf2f((ushort_t)(u.y & 0xffffu)); vals[3] = bf2f((ushort_t)(u.y >> 16));
    vals[4] = bf2f((ushort_t)(u.z & 0xffffu)); vals[5] = bf2f((ushort_t)(u.z >> 16));
    vals[6] = bf2f((ushort_t)(u.w & 0xffffu)); vals[7] = bf2f((ushort_t)(u.w >> 16));
#pragma unroll
    for (int j = 0; j < 8; ++j)
      if (v0 + j < V_) out[obase + v0 + j] = vals[j] - lse;
  }
}

extern "C" void kernel_launch(void* const* d_in, const int* in_sizes, int n_in,
                              void* d_out, int out_size, void* d_ws, size_t ws_size,
                              hipStream_t stream) {
  const float* enc_h  = (const float*)d_in[0];
  const float* keys   = (const float*)d_in[1];
  const int*   tgt    = (const int*)d_in[2];
  const float* emb    = (const float*)d_in[3];
  const float* Wa_w   = (const float*)d_in[4];
  const float* Wa_b   = (const float*)d_in[5];
  const float* Ua_w   = (const float*)d_in[6];
  const float* Ua_b   = (const float*)d_in[7];
  const float* Va_w   = (const float*)d_in[8];
  const float* Va_b   = (const float*)d_in[9];
  const float* W_ih   = (const float*)d_in[10];
  const float* b_ih   = (const float*)d_in[11];
  const float* W_hh   = (const float*)d_in[12];
  const float* b_hh   = (const float*)d_in[13];
  const float* out_w  = (const float*)d_in[14];
  const float* out_b  = (const float*)d_in[15];
  float* out = (float*)d_out;
  (void)d_ws; (void)ws_size;

  hipLaunchKernelGGL(k_pre, dim3(966), dim3(256), 0, stream,
                     keys, Ua_w, Ua_b, Wa_b, W_hh, Wa_w, W_ih, b_ih, tgt, emb);
  hipLaunchKernelGGL(k_recur, dim3(32 + 1792), dim3(1024), 0, stream,
                     enc_h, Va_w, Va_b, b_hh, out_w, out);
  hipLaunchKernelGGL(k_logits, dim3(393), dim3(512), 0, stream, out_b);
  hipLaunchKernelGGL(k_wlse, dim3(4, NROW), dim3(256), 0, stream, out);
}

// Round 21
// 444.453 us; speedup vs baseline: 1.1226x; 1.1226x over previous
//
#include <hip/hip_runtime.h>
#include <math.h>

#define B_ 32
#define S_ 50
#define H_ 256
#define T_ 25
#define V_ 50257
#define VP 50264    /* padded g_lgt row */
#define NCH 786     /* 393 n-blocks x 2 wave-cols */
#define NROW (B_ * T_)
#define NWROW 1024  /* 256 Wa + 768 W_hh */
#define VT_ 3144    /* 393 * 8 vocab 16-col tiles */
#define MROW 54     /* padded M row (ushorts): 27 u32, gcd(27,32)=1 */
#define SOS 0

typedef unsigned short ushort_t;
typedef __attribute__((ext_vector_type(8))) unsigned short ushort8;
typedef __attribute__((ext_vector_type(8))) short short8v;
typedef __attribute__((ext_vector_type(4))) float f32x4;
typedef _Float16 half2v __attribute__((ext_vector_type(2)));

// ---- static device scratch (loader-allocated; fully rewritten each call)
__device__ ushort_t g_ua[B_ * S_ * H_];          // bf16 ua_keys + (Ua_b+Wa_b) folded
__device__ ushort_t g_hbf[NROW * H_];            // bf16 h2, row m = b*T+t
__device__ float    g_gie[T_ * B_ * 3 * H_];     // W_ih[:,:256].emb + b_ih
__device__ ushort_t g_wpk[(size_t)VT_ * 32 * 16 * 8];  // out_w bf16, fragment-major
__device__ ushort_t g_wcat[NWROW * H_];          // packed F16 [Wa; W_hh], K=256
__device__ ushort_t g_MT2[B_ * 768 * MROW];      // M[j][s] F16 padded rows
__device__ ushort_t g_lgt[(size_t)NROW * VP];    // bf16 logits staging (80 MB, padded)
__device__ float    g_psum[NROW * NCH];

__device__ __forceinline__ float bf2f(ushort_t h) {
  union { unsigned int u; float f; } c; c.u = ((unsigned int)h) << 16; return c.f;
}
__device__ __forceinline__ ushort_t f2bf(float f) {
  union { float f; unsigned int u; } c; c.f = f;
  unsigned int u = c.u;
  return (ushort_t)((u + 0x7FFFu + ((u >> 16) & 1u)) >> 16);
}
__device__ __forceinline__ ushort_t f2h(float f) {
  union { _Float16 h; ushort_t u; } c; c.h = (_Float16)f; return c.u;
}
__device__ __forceinline__ float dot2(unsigned int a, unsigned int b, float c) {
#if __has_builtin(__builtin_amdgcn_fdot2)
  union { unsigned int u; half2v h; } ca, cb;
  ca.u = a; cb.u = b;
  return __builtin_amdgcn_fdot2(ca.h, cb.h, c, false);
#else
  union { unsigned int u; _Float16 h[2]; } ca, cb;
  ca.u = a; cb.u = b;
  return c + (float)ca.h[0] * (float)cb.h[0] + (float)ca.h[1] * (float)cb.h[1];
#endif
}
__device__ __forceinline__ float tanh_fast(float x) {
  const float e = __expf(2.f * x);
  return 1.f - 2.f / (e + 1.f);
}

// ---------------- ONE setup launch, role by block range:
// [0,26): ua MFMA | [26,410): M | [410,710): gie | [710,966): wcat
__global__ void k_pre(const float* __restrict__ keys, const float* __restrict__ Ua_w,
                      const float* __restrict__ Ua_b, const float* __restrict__ Wa_b,
                      const float* __restrict__ W_hh, const float* __restrict__ Wa_w,
                      const float* __restrict__ W_ih, const float* __restrict__ b_ih,
                      const int* __restrict__ tgt, const float* __restrict__ emb_tab) {
  __shared__ float sbuf[16384];   // 64 KB, aliased per role
  const int bid = blockIdx.x, tid = threadIdx.x;

  if (bid < 26) {
    // ---- ua MFMA: ua[r=(b,s)][g] = keys_bf16[r,:] . Ua_w[g,:] + (Ua_b+Wa_b)[g]
    ushort_t* sA = (ushort_t*)sbuf;
    const int bx = bid & 1, by = bid >> 1;
    const int n0 = bx * 128, m0 = by * 128;
    const int lane = tid & 63, wv = tid >> 6;
    const int wm = wv >> 1, wn = wv & 1;
    const int l16 = lane & 15, l4 = lane >> 4;

    for (int i = tid; i < 128 * 32; i += 256) {
      const int row = i >> 5, ks = i & 31;
      const int m = m0 + row;
      ushort8 val = {0, 0, 0, 0, 0, 0, 0, 0};
      if (m < B_ * S_) {
        const float4* kr = (const float4*)(keys + (size_t)m * H_ + ks * 8);
        const float4 f0 = kr[0], f1 = kr[1];
        val[0] = f2bf(f0.x); val[1] = f2bf(f0.y); val[2] = f2bf(f0.z); val[3] = f2bf(f0.w);
        val[4] = f2bf(f1.x); val[5] = f2bf(f1.y); val[6] = f2bf(f1.z); val[7] = f2bf(f1.w);
      }
      *(ushort8*)((char*)sA + row * 512 + ((ks ^ (row & 7)) << 4)) = val;
    }
    __syncthreads();

    f32x4 acc[4][4];
#pragma unroll
    for (int mi = 0; mi < 4; ++mi)
#pragma unroll
      for (int ni = 0; ni < 4; ++ni) acc[mi][ni] = (f32x4){0.f, 0.f, 0.f, 0.f};

#pragma unroll 1
    for (int kk = 0; kk < 8; ++kk) {
      short8v a[4], bfr[4];
#pragma unroll
      for (int mi = 0; mi < 4; ++mi) {
        const int row = wm * 64 + mi * 16 + l16;
        const int ks = kk * 4 + l4;
        a[mi] = *(const short8v*)((const char*)sA + row * 512 + ((ks ^ (row & 7)) << 4));
      }
#pragma unroll
      for (int ni = 0; ni < 4; ++ni) {
        const int g = n0 + wn * 64 + ni * 16 + l16;
        const float4* wr = (const float4*)(Ua_w + (size_t)g * H_ + kk * 32 + l4 * 8);
        const float4 f0 = wr[0], f1 = wr[1];
        short8v bv;
        bv[0] = (short)f2bf(f0.x); bv[1] = (short)f2bf(f0.y);
        bv[2] = (short)f2bf(f0.z); bv[3] = (short)f2bf(f0.w);
        bv[4] = (short)f2bf(f1.x); bv[5] = (short)f2bf(f1.y);
        bv[6] = (short)f2bf(f1.z); bv[7] = (short)f2bf(f1.w);
        bfr[ni] = bv;
      }
#pragma unroll
      for (int mi = 0; mi < 4; ++mi)
#pragma unroll
        for (int ni = 0; ni < 4; ++ni)
          acc[mi][ni] = __builtin_amdgcn_mfma_f32_16x16x32_bf16(a[mi], bfr[ni], acc[mi][ni], 0, 0, 0);
    }

    int col[4]; float bias[4];
#pragma unroll
    for (int ni = 0; ni < 4; ++ni) {
      col[ni] = n0 + wn * 64 + ni * 16 + l16;
      bias[ni] = Ua_b[col[ni]] + Wa_b[col[ni]];
    }
#pragma unroll
    for (int mi = 0; mi < 4; ++mi) {
#pragma unroll
      for (int j = 0; j < 4; ++j) {
        const int m = m0 + wm * 64 + mi * 16 + l4 * 4 + j;
        if (m < B_ * S_) {
#pragma unroll
          for (int ni = 0; ni < 4; ++ni)
            g_ua[(size_t)m * H_ + col[ni]] = f2bf(acc[mi][ni][j] + bias[ni]);
        }
      }
    }
  } else if (bid < 410) {
    // ---- M[j][s] = W_ih[j,256:] . keys[b,s,:]  (F16 out)
    const int cc = bid - 26;
    const int c = cc % 12, b = cc / 12;
    {
      const float4* src = (const float4*)(keys + (size_t)b * S_ * H_);
      float4* dst = (float4*)sbuf;
      for (int i = tid; i < S_ * H_ / 4; i += 256) dst[i] = src[i];
    }
    __syncthreads();
    const int sub = tid & 15, grp = tid >> 4;
#pragma unroll 1
    for (int it = 0; it < 4; ++it) {
      const int j = c * 64 + it * 16 + grp;
      float w16[16];
#pragma unroll
      for (int kp = 0; kp < 16; ++kp)
        w16[kp] = W_ih[(size_t)j * (2 * H_) + H_ + sub + 16 * kp];
#pragma unroll 1
      for (int s = 0; s < S_; ++s) {
        float a = 0.f;
#pragma unroll
        for (int kp = 0; kp < 16; ++kp) a += w16[kp] * sbuf[s * H_ + sub + 16 * kp];
        a += __shfl_xor(a, 8); a += __shfl_xor(a, 4);
        a += __shfl_xor(a, 2); a += __shfl_xor(a, 1);
        if (sub == 0) g_MT2[(size_t)b * 768 * MROW + j * MROW + s] = f2h(a);
      }
    }
  } else if (bid < 710) {
    // ---- gie[t][b][j] = emb(tok[t,b]) . W_ih[j,:256] + b_ih[j]
    const int cc = bid - 410;
    const int chunk = cc % 12, t = cc / 12;
    for (int i = tid; i < B_ * H_; i += 256) {
      const int b = i >> 8, g = i & 255;
      const int tok = (t == 0) ? SOS : tgt[b * T_ + (t - 1)];
      sbuf[i] = emb_tab[(size_t)tok * H_ + g];
    }
    __syncthreads();
    const int vl = tid & 63, wd = tid >> 6;
    const int j = chunk * 64 + vl;
    const float4* wrow = (const float4*)(W_ih + (size_t)j * (2 * H_));
    const float4* se4 = (const float4*)sbuf;
    float acc[8];
    const float base = b_ih[j];
#pragma unroll
    for (int bb = 0; bb < 8; ++bb) acc[bb] = base;
    for (int k4 = 0; k4 < 64; ++k4) {
      const float4 w = wrow[k4];
#pragma unroll
      for (int bb = 0; bb < 8; ++bb) {
        const float4 x = se4[(wd * 8 + bb) * 64 + k4];
        acc[bb] += w.x * x.x + w.y * x.y + w.z * x.z + w.w * x.w;
      }
    }
#pragma unroll
    for (int bb = 0; bb < 8; ++bb)
      g_gie[((size_t)t * B_ + (wd * 8 + bb)) * (3 * H_) + j] = acc[bb];
  } else {
    // ---- wcat pack: [Wa; W_hh] -> F16
    const size_t i0 = (size_t)(bid - 710) * 256 + tid;
    for (size_t i = i0; i < (size_t)NWROW * H_; i += 256u * 256u) {
      const int r = (int)(i >> 8), k = (int)(i & 255);
      const float v = (r < 256) ? Wa_w[r * H_ + k] : W_hh[(r - 256) * H_ + k];
      g_wcat[i] = f2h(v);
    }
  }
}

// ---------------- recurrence (blocks 0..31) + g_wpk pack (blocks 32..) in ONE launch.
__global__ void __launch_bounds__(1024, 1)
k_recur(const float* __restrict__ enc_h, const float* __restrict__ Va_w,
        const float* __restrict__ Va_b, const float* __restrict__ b_hh,
        const float* __restrict__ out_w, float* __restrict__ out) {
  __shared__ ushort_t s_ua[S_ * H_];       // 25.6 KB bf16
  __shared__ ushort_t s_M[768 * MROW];     // 81 KB f16, [j][54]
  __shared__ float s_res[NWROW];           // 4 KB
  __shared__ float s_mw[768];              // 3 KB
  __shared__ ushort_t s_hh[H_];            // f16 h (dot2 operand)
  __shared__ ushort_t s_wh[64];            // f16 attention weights
  __shared__ float s_va[H_];
  __shared__ float s_score[64];
  const int bidx = blockIdx.x, tid = threadIdx.x;

  if (bidx >= 32) {
    // ---- pack out_w into fragment-major g_wpk (bf16): p = (vt*32 + kg)*16 + c
    const size_t total = (size_t)VT_ * 32 * 16;
    for (size_t p = (size_t)(bidx - 32) * 1024 + tid; p < total;
         p += (size_t)(gridDim.x - 32) * 1024) {
      const int c = (int)(p & 15);
      const int kg = (int)((p >> 4) & 31);
      const int vt = (int)(p >> 9);
      const int v = vt * 16 + c;
      short8v val = {0, 0, 0, 0, 0, 0, 0, 0};
      if (v < V_) {
        const float4* owr = (const float4*)(out_w + (size_t)v * H_ + kg * 8);
        const float4 f0 = owr[0], f1 = owr[1];
        val[0] = (short)f2bf(f0.x); val[1] = (short)f2bf(f0.y);
        val[2] = (short)f2bf(f0.z); val[3] = (short)f2bf(f0.w);
        val[4] = (short)f2bf(f1.x); val[5] = (short)f2bf(f1.y);
        val[6] = (short)f2bf(f1.z); val[7] = (short)f2bf(f1.w);
      }
      ((short8v*)g_wpk)[p] = val;
    }
    return;
  }

  const int b = bidx;
  const int lane = tid & 63, wid = tid >> 6;
  const int sub = lane & 15;
  const int grp = tid >> 4;            // 0..63 row-slot (16 lanes per row)

  {
    const uint4* src = (const uint4*)(g_ua + (size_t)b * S_ * H_);
    uint4* dst = (uint4*)s_ua;
    for (int i = tid; i < S_ * H_ / 8; i += 1024) dst[i] = src[i];
    const uint4* src2 = (const uint4*)(g_MT2 + (size_t)b * 768 * MROW);
    uint4* dst2 = (uint4*)s_M;
    for (int i = tid; i < 768 * MROW / 8; i += 1024) dst2[i] = src2[i];
  }
  float hreg = 0.f, bhh0 = 0.f, bhh1 = 0.f, bhh2 = 0.f;
  if (tid < H_) {
    hreg = enc_h[b * H_ + tid];
    s_hh[tid] = f2h(hreg);
    s_va[tid] = Va_w[tid];
    bhh0 = b_hh[tid]; bhh1 = b_hh[H_ + tid]; bhh2 = b_hh[2 * H_ + tid];
  }
  const float vab = Va_b[0];
  __syncthreads();

  for (int t = 0; t < T_; ++t) {
    float gie0 = 0.f, gie1 = 0.f, gie2 = 0.f;
    if (tid < H_) {
      const float* gp = g_gie + ((size_t)t * B_ + b) * (3 * H_);
      gie0 = gp[tid]; gie1 = gp[H_ + tid]; gie2 = gp[2 * H_ + tid];
    }

    // ---- phase A: coalesced f16-dot2 sweep s_res[0..1024) = g_wcat . h
    {
      const unsigned int* hh = (const unsigned int*)s_hh;
#pragma unroll 4
      for (int it = 0; it < 16; ++it) {
        const int row = it * 64 + grp;
        const uint4* wr = (const uint4*)(g_wcat + (size_t)row * H_);
        const uint4 w0 = wr[sub], w1 = wr[16 + sub];
        float a = 0.f;
        a = dot2(w0.x, hh[sub * 4 + 0], a);
        a = dot2(w0.y, hh[sub * 4 + 1], a);
        a = dot2(w0.z, hh[sub * 4 + 2], a);
        a = dot2(w0.w, hh[sub * 4 + 3], a);
        a = dot2(w1.x, hh[64 + sub * 4 + 0], a);
        a = dot2(w1.y, hh[64 + sub * 4 + 1], a);
        a = dot2(w1.z, hh[64 + sub * 4 + 2], a);
        a = dot2(w1.w, hh[64 + sub * 4 + 3], a);
        a += __shfl_xor(a, 8); a += __shfl_xor(a, 4);
        a += __shfl_xor(a, 2); a += __shfl_xor(a, 1);
        if (sub == 0) s_res[row] = a;
      }
    }
    __syncthreads();

    // ---- phase B: scores
    for (int s = wid; s < S_; s += 16) {
      const ushort_t* uarow = s_ua + s * H_;
      float acc = 0.f;
#pragma unroll
      for (int i = 0; i < 4; ++i) {
        const int gg = lane + i * 64;
        acc += tanh_fast(s_res[gg] + bf2f(uarow[gg])) * s_va[gg];
      }
      for (int off = 32; off > 0; off >>= 1) acc += __shfl_xor(acc, off);
      if (lane == 0) s_score[s] = acc + vab;
    }
    __syncthreads();

    // ---- phase C: softmax on wave 0; write attention output
    if (tid < 64) {
      const float v = (tid < S_) ? s_score[tid] : -INFINITY;
      float m = v;
      for (int off = 32; off > 0; off >>= 1) m = fmaxf(m, __shfl_xor(m, off));
      const float e = (tid < S_) ? __expf(v - m) : 0.f;
      float ssum = e;
      for (int off = 32; off > 0; off >>= 1) ssum += __shfl_xor(ssum, off);
      const float w = e / ssum;
      if (tid < S_) {
        s_wh[tid] = f2h(w);
        out[(size_t)B_ * T_ * V_ + (size_t)B_ * H_ + (size_t)(b * T_ + t) * S_ + tid] = w;
      }
    }
    __syncthreads();

    // ---- phase D1: 768 threads, f16-dot2 M.w (25 u32 pairs, conflict-free stride-27)
    if (tid < 768) {
      const unsigned int* m32 = (const unsigned int*)s_M + tid * (MROW / 2);
      const unsigned int* ww = (const unsigned int*)s_wh;
      float acc = 0.f;
#pragma unroll
      for (int i = 0; i < 25; ++i) acc = dot2(m32[i], ww[i], acc);
      s_mw[tid] = acc;
    }
    __syncthreads();

    // ---- phase D2: GRU finish + h update
    if (tid < H_) {
      const float gi0 = gie0 + s_mw[tid];
      const float gi1 = gie1 + s_mw[H_ + tid];
      const float gi2 = gie2 + s_mw[2 * H_ + tid];
      const float gh0 = s_res[256 + tid] + bhh0;
      const float gh1 = s_res[512 + tid] + bhh1;
      const float gh2 = s_res[768 + tid] + bhh2;
      const float r = 1.f / (1.f + __expf(-(gi0 + gh0)));
      const float z = 1.f / (1.f + __expf(-(gi1 + gh1)));
      const float n = tanh_fast(gi2 + r * gh2);
      const float h2 = (1.f - z) * n + z * hreg;
      hreg = h2;
      s_hh[tid] = f2h(h2);
      g_hbf[((size_t)b * T_ + t) * H_ + tid] = f2bf(h2);
      if (t == T_ - 1) out[(size_t)B_ * T_ * V_ + b * H_ + tid] = h2;
    }
    __syncthreads();
  }
}

// ---------------- MFMA logits GEMM, B staged in LDS once, loop all 7 m-tiles.
// Epilogue: fixed-max softmax partials (logits bounded ~|12| << f32 range).
__global__ void __launch_bounds__(512, 1)
k_logits(const float* __restrict__ out_b) {
  __shared__ ushort_t sA[128 * 256];   // 64 KB, XOR-swizzled rows
  __shared__ ushort_t sB[128 * 256];   // 64 KB, fragment-major copy of this block's B
  const int tid = threadIdx.x, nb = blockIdx.x;
  const int n0 = nb * 128;
  const int lane = tid & 63, wv = tid >> 6;
  const int wm = wv >> 1, wn = wv & 1;          // 4 x 2
  const int l16 = lane & 15, l4 = lane >> 4;

  // stage B once: 8 local vocab-16 tiles = 4096 short8v
  {
    const short8v* src = (const short8v*)g_wpk + (size_t)nb * 4096;
    short8v* dst = (short8v*)sB;
    for (int i = tid; i < 4096; i += 512) dst[i] = src[i];
  }

  int vcol[4]; float bias[4]; bool valid[4];
#pragma unroll
  for (int ni = 0; ni < 4; ++ni) {
    vcol[ni] = n0 + wn * 64 + ni * 16 + l16;
    valid[ni] = (vcol[ni] < V_);
    bias[ni] = valid[ni] ? out_b[vcol[ni]] : 0.f;
  }
  const int chunk = nb * 2 + wn;

#pragma unroll 1
  for (int mt = 0; mt < 7; ++mt) {
    const int m0 = mt * 128;
    __syncthreads();   // protect sA from previous iteration's readers; covers sB stage at mt=0
    for (int i = tid; i < 128 * 32; i += 512) {
      const int row = i >> 5, ks = i & 31;
      const int m = m0 + row;
      ushort8 val;
      if (m < NROW) val = ((const ushort8*)(g_hbf + (size_t)m * H_))[ks];
      else { ushort8 z = {0, 0, 0, 0, 0, 0, 0, 0}; val = z; }
      *(ushort8*)((char*)sA + row * 512 + ((ks ^ (row & 7)) << 4)) = val;
    }
    __syncthreads();

    f32x4 acc[2][4];
#pragma unroll
    for (int mi = 0; mi < 2; ++mi)
#pragma unroll
      for (int ni = 0; ni < 4; ++ni) acc[mi][ni] = (f32x4){0.f, 0.f, 0.f, 0.f};

#pragma unroll 1
    for (int kk = 0; kk < 8; ++kk) {
      short8v a[2], bfr[4];
#pragma unroll
      for (int mi = 0; mi < 2; ++mi) {
        const int row = wm * 32 + mi * 16 + l16;
        const int ks = kk * 4 + l4;
        a[mi] = *(const short8v*)((const char*)sA + row * 512 + ((ks ^ (row & 7)) << 4));
      }
#pragma unroll
      for (int ni = 0; ni < 4; ++ni)
        bfr[ni] = ((const short8v*)sB)[(((wn * 4 + ni) * 32) + kk * 4 + l4) * 16 + l16];
#pragma unroll
      for (int mi = 0; mi < 2; ++mi)
#pragma unroll
        for (int ni = 0; ni < 4; ++ni)
          acc[mi][ni] = __builtin_amdgcn_mfma_f32_16x16x32_bf16(a[mi], bfr[ni], acc[mi][ni], 0, 0, 0);
    }

#pragma unroll
    for (int mi = 0; mi < 2; ++mi) {
#pragma unroll
      for (int j = 0; j < 4; ++j) {
        const int m = m0 + wm * 32 + mi * 16 + l4 * 4 + j;
        float vv[4];
        float es = 0.f;
#pragma unroll
        for (int ni = 0; ni < 4; ++ni) {
          vv[ni] = acc[mi][ni][j] + bias[ni];
          if (valid[ni]) es += __expf(vv[ni]);
        }
        es += __shfl_xor(es, 1); es += __shfl_xor(es, 2);
        es += __shfl_xor(es, 4); es += __shfl_xor(es, 8);
        if (m < NROW) {
#pragma unroll
          for (int ni = 0; ni < 4; ++ni)
            if (valid[ni]) g_lgt[(size_t)m * VP + vcol[ni]] = f2bf(vv[ni]);
          if (l16 == 0) g_psum[(size_t)m * NCH + chunk] = es;
        }
      }
    }
  }
}

// ---------------- lse[r]=log(sum psum) + in-place write (u32-paired). grid 800 x 256
__global__ void k_wlse(float* __restrict__ out) {
  __shared__ float red[4];
  const int r = blockIdx.x;
  const int tid = threadIdx.x;
  float s = 0.f;
  for (int i = tid; i < NCH; i += 256) s += g_psum[(size_t)r * NCH + i];
  for (int off = 32; off > 0; off >>= 1) s += __shfl_xor(s, off);
  if ((tid & 63) == 0) red[tid >> 6] = s;
  __syncthreads();
  s = red[0] + red[1] + red[2] + red[3];
  float lse = logf(s);
  if (!isfinite(lse)) lse = 0.f;
  const size_t obase = (size_t)r * V_;
  const unsigned int* row32 = (const unsigned int*)(g_lgt + (size_t)r * VP);
#pragma unroll 1
  for (int i = tid; i < V_ / 2; i += 256) {
    const unsigned int u = row32[i];
    out[obase + 2 * i]     = bf2f((ushort_t)(u & 0xffffu)) - lse;
    out[obase + 2 * i + 1] = bf2f((ushort_t)(u >> 16)) - lse;
  }
  if (tid == 0)
    out[obase + V_ - 1] = bf2f(g_lgt[(size_t)r * VP + V_ - 1]) - lse;
}

extern "C" void kernel_launch(void* const* d_in, const int* in_sizes, int n_in,
                              void* d_out, int out_size, void* d_ws, size_t ws_size,
                              hipStream_t stream) {
  const float* enc_h  = (const float*)d_in[0];
  const float* keys   = (const float*)d_in[1];
  const int*   tgt    = (const int*)d_in[2];
  const float* emb    = (const float*)d_in[3];
  const float* Wa_w   = (const float*)d_in[4];
  const float* Wa_b   = (const float*)d_in[5];
  const float* Ua_w   = (const float*)d_in[6];
  const float* Ua_b   = (const float*)d_in[7];
  const float* Va_w   = (const float*)d_in[8];
  const float* Va_b   = (const float*)d_in[9];
  const float* W_ih   = (const float*)d_in[10];
  const float* b_ih   = (const float*)d_in[11];
  const float* W_hh   = (const float*)d_in[12];
  const float* b_hh   = (const float*)d_in[13];
  const float* out_w  = (const float*)d_in[14];
  const float* out_b  = (const float*)d_in[15];
  float* out = (float*)d_out;
  (void)d_ws; (void)ws_size;

  hipLaunchKernelGGL(k_pre, dim3(966), dim3(256), 0, stream,
                     keys, Ua_w, Ua_b, Wa_b, W_hh, Wa_w, W_ih, b_ih, tgt, emb);
  hipLaunchKernelGGL(k_recur, dim3(32 + 1792), dim3(1024), 0, stream,
                     enc_h, Va_w, Va_b, b_hh, out_w, out);
  hipLaunchKernelGGL(k_logits, dim3(393), dim3(512), 0, stream, out_b);
  hipLaunchKernelGGL(k_wlse, dim3(NROW), dim3(256), 0, stream, out);
}

// Round 22
// 440.434 us; speedup vs baseline: 1.1328x; 1.0091x over previous
//
#include <hip/hip_runtime.h>
#include <math.h>

#define B_ 32
#define S_ 50
#define H_ 256
#define T_ 25
#define V_ 50257
#define VP 50264    /* padded g_lgt row */
#define NROW (B_ * T_)
#define NWROW 1024  /* 256 Wa + 768 W_hh */
#define VT_ 3144    /* 393 * 8 vocab 16-col tiles */
#define MROW 54     /* padded M row (ushorts): 27 u32, gcd(27,32)=1 */
#define SOS 0

typedef unsigned short ushort_t;
typedef __attribute__((ext_vector_type(8))) unsigned short ushort8;
typedef __attribute__((ext_vector_type(8))) short short8v;
typedef __attribute__((ext_vector_type(4))) float f32x4;
typedef _Float16 half2v __attribute__((ext_vector_type(2)));

// ---- static device scratch (loader-allocated; fully rewritten each call)
__device__ ushort_t g_ua[B_ * S_ * H_];          // bf16 ua_keys + (Ua_b+Wa_b) folded
__device__ ushort_t g_hbf[NROW * H_];            // bf16 h2, row m = b*T+t
__device__ float    g_gie[T_ * B_ * 3 * H_];     // W_ih[:,:256].emb + b_ih
__device__ ushort_t g_wpk[(size_t)VT_ * 32 * 16 * 8];  // out_w bf16, fragment-major
__device__ ushort_t g_wcat[NWROW * H_];          // packed F16 [Wa; W_hh], K=256
__device__ ushort_t g_MT2[B_ * 768 * MROW];      // M[j][s] F16 padded rows
__device__ ushort_t g_lgt[(size_t)NROW * VP];    // bf16 logits staging (80 MB, padded)

__device__ __forceinline__ float bf2f(ushort_t h) {
  union { unsigned int u; float f; } c; c.u = ((unsigned int)h) << 16; return c.f;
}
__device__ __forceinline__ ushort_t f2bf(float f) {
  union { float f; unsigned int u; } c; c.f = f;
  unsigned int u = c.u;
  return (ushort_t)((u + 0x7FFFu + ((u >> 16) & 1u)) >> 16);
}
__device__ __forceinline__ ushort_t f2h(float f) {
  union { _Float16 h; ushort_t u; } c; c.h = (_Float16)f; return c.u;
}
__device__ __forceinline__ float dot2(unsigned int a, unsigned int b, float c) {
#if __has_builtin(__builtin_amdgcn_fdot2)
  union { unsigned int u; half2v h; } ca, cb;
  ca.u = a; cb.u = b;
  return __builtin_amdgcn_fdot2(ca.h, cb.h, c, false);
#else
  union { unsigned int u; _Float16 h[2]; } ca, cb;
  ca.u = a; cb.u = b;
  return c + (float)ca.h[0] * (float)cb.h[0] + (float)ca.h[1] * (float)cb.h[1];
#endif
}
__device__ __forceinline__ float tanh_fast(float x) {
  const float e = __expf(2.f * x);
  return 1.f - 2.f / (e + 1.f);
}

// ---------------- ONE setup launch, role by block range:
// [0,26): ua MFMA | [26,410): M | [410,710): gie | [710,966): wcat
__global__ void k_pre(const float* __restrict__ keys, const float* __restrict__ Ua_w,
                      const float* __restrict__ Ua_b, const float* __restrict__ Wa_b,
                      const float* __restrict__ W_hh, const float* __restrict__ Wa_w,
                      const float* __restrict__ W_ih, const float* __restrict__ b_ih,
                      const int* __restrict__ tgt, const float* __restrict__ emb_tab) {
  __shared__ float sbuf[16384];   // 64 KB, aliased per role
  const int bid = blockIdx.x, tid = threadIdx.x;

  if (bid < 26) {
    // ---- ua MFMA: ua[r=(b,s)][g] = keys_bf16[r,:] . Ua_w[g,:] + (Ua_b+Wa_b)[g]
    ushort_t* sA = (ushort_t*)sbuf;
    const int bx = bid & 1, by = bid >> 1;
    const int n0 = bx * 128, m0 = by * 128;
    const int lane = tid & 63, wv = tid >> 6;
    const int wm = wv >> 1, wn = wv & 1;
    const int l16 = lane & 15, l4 = lane >> 4;

    for (int i = tid; i < 128 * 32; i += 256) {
      const int row = i >> 5, ks = i & 31;
      const int m = m0 + row;
      ushort8 val = {0, 0, 0, 0, 0, 0, 0, 0};
      if (m < B_ * S_) {
        const float4* kr = (const float4*)(keys + (size_t)m * H_ + ks * 8);
        const float4 f0 = kr[0], f1 = kr[1];
        val[0] = f2bf(f0.x); val[1] = f2bf(f0.y); val[2] = f2bf(f0.z); val[3] = f2bf(f0.w);
        val[4] = f2bf(f1.x); val[5] = f2bf(f1.y); val[6] = f2bf(f1.z); val[7] = f2bf(f1.w);
      }
      *(ushort8*)((char*)sA + row * 512 + ((ks ^ (row & 7)) << 4)) = val;
    }
    __syncthreads();

    f32x4 acc[4][4];
#pragma unroll
    for (int mi = 0; mi < 4; ++mi)
#pragma unroll
      for (int ni = 0; ni < 4; ++ni) acc[mi][ni] = (f32x4){0.f, 0.f, 0.f, 0.f};

#pragma unroll 1
    for (int kk = 0; kk < 8; ++kk) {
      short8v a[4], bfr[4];
#pragma unroll
      for (int mi = 0; mi < 4; ++mi) {
        const int row = wm * 64 + mi * 16 + l16;
        const int ks = kk * 4 + l4;
        a[mi] = *(const short8v*)((const char*)sA + row * 512 + ((ks ^ (row & 7)) << 4));
      }
#pragma unroll
      for (int ni = 0; ni < 4; ++ni) {
        const int g = n0 + wn * 64 + ni * 16 + l16;
        const float4* wr = (const float4*)(Ua_w + (size_t)g * H_ + kk * 32 + l4 * 8);
        const float4 f0 = wr[0], f1 = wr[1];
        short8v bv;
        bv[0] = (short)f2bf(f0.x); bv[1] = (short)f2bf(f0.y);
        bv[2] = (short)f2bf(f0.z); bv[3] = (short)f2bf(f0.w);
        bv[4] = (short)f2bf(f1.x); bv[5] = (short)f2bf(f1.y);
        bv[6] = (short)f2bf(f1.z); bv[7] = (short)f2bf(f1.w);
        bfr[ni] = bv;
      }
#pragma unroll
      for (int mi = 0; mi < 4; ++mi)
#pragma unroll
        for (int ni = 0; ni < 4; ++ni)
          acc[mi][ni] = __builtin_amdgcn_mfma_f32_16x16x32_bf16(a[mi], bfr[ni], acc[mi][ni], 0, 0, 0);
    }

    int col[4]; float bias[4];
#pragma unroll
    for (int ni = 0; ni < 4; ++ni) {
      col[ni] = n0 + wn * 64 + ni * 16 + l16;
      bias[ni] = Ua_b[col[ni]] + Wa_b[col[ni]];
    }
#pragma unroll
    for (int mi = 0; mi < 4; ++mi) {
#pragma unroll
      for (int j = 0; j < 4; ++j) {
        const int m = m0 + wm * 64 + mi * 16 + l4 * 4 + j;
        if (m < B_ * S_) {
#pragma unroll
          for (int ni = 0; ni < 4; ++ni)
            g_ua[(size_t)m * H_ + col[ni]] = f2bf(acc[mi][ni][j] + bias[ni]);
        }
      }
    }
  } else if (bid < 410) {
    // ---- M[j][s] = W_ih[j,256:] . keys[b,s,:]  (F16 out)
    const int cc = bid - 26;
    const int c = cc % 12, b = cc / 12;
    {
      const float4* src = (const float4*)(keys + (size_t)b * S_ * H_);
      float4* dst = (float4*)sbuf;
      for (int i = tid; i < S_ * H_ / 4; i += 256) dst[i] = src[i];
    }
    __syncthreads();
    const int sub = tid & 15, grp = tid >> 4;
#pragma unroll 1
    for (int it = 0; it < 4; ++it) {
      const int j = c * 64 + it * 16 + grp;
      float w16[16];
#pragma unroll
      for (int kp = 0; kp < 16; ++kp)
        w16[kp] = W_ih[(size_t)j * (2 * H_) + H_ + sub + 16 * kp];
#pragma unroll 1
      for (int s = 0; s < S_; ++s) {
        float a = 0.f;
#pragma unroll
        for (int kp = 0; kp < 16; ++kp) a += w16[kp] * sbuf[s * H_ + sub + 16 * kp];
        a += __shfl_xor(a, 8); a += __shfl_xor(a, 4);
        a += __shfl_xor(a, 2); a += __shfl_xor(a, 1);
        if (sub == 0) g_MT2[(size_t)b * 768 * MROW + j * MROW + s] = f2h(a);
      }
    }
  } else if (bid < 710) {
    // ---- gie[t][b][j] = emb(tok[t,b]) . W_ih[j,:256] + b_ih[j]
    const int cc = bid - 410;
    const int chunk = cc % 12, t = cc / 12;
    for (int i = tid; i < B_ * H_; i += 256) {
      const int b = i >> 8, g = i & 255;
      const int tok = (t == 0) ? SOS : tgt[b * T_ + (t - 1)];
      sbuf[i] = emb_tab[(size_t)tok * H_ + g];
    }
    __syncthreads();
    const int vl = tid & 63, wd = tid >> 6;
    const int j = chunk * 64 + vl;
    const float4* wrow = (const float4*)(W_ih + (size_t)j * (2 * H_));
    const float4* se4 = (const float4*)sbuf;
    float acc[8];
    const float base = b_ih[j];
#pragma unroll
    for (int bb = 0; bb < 8; ++bb) acc[bb] = base;
    for (int k4 = 0; k4 < 64; ++k4) {
      const float4 w = wrow[k4];
#pragma unroll
      for (int bb = 0; bb < 8; ++bb) {
        const float4 x = se4[(wd * 8 + bb) * 64 + k4];
        acc[bb] += w.x * x.x + w.y * x.y + w.z * x.z + w.w * x.w;
      }
    }
#pragma unroll
    for (int bb = 0; bb < 8; ++bb)
      g_gie[((size_t)t * B_ + (wd * 8 + bb)) * (3 * H_) + j] = acc[bb];
  } else {
    // ---- wcat pack: [Wa; W_hh] -> F16
    const size_t i0 = (size_t)(bid - 710) * 256 + tid;
    for (size_t i = i0; i < (size_t)NWROW * H_; i += 256u * 256u) {
      const int r = (int)(i >> 8), k = (int)(i & 255);
      const float v = (r < 256) ? Wa_w[r * H_ + k] : W_hh[(r - 256) * H_ + k];
      g_wcat[i] = f2h(v);
    }
  }
}

// ---------------- recurrence (blocks 0..31) + g_wpk pack (blocks 32..) in ONE launch.
// Per step: [dot2 sweep | bar | scores | bar | softmax | bar | fused M.w+GRU | bar]
__global__ void __launch_bounds__(1024, 1)
k_recur(const float* __restrict__ enc_h, const float* __restrict__ Va_w,
        const float* __restrict__ Va_b, const float* __restrict__ b_hh,
        const float* __restrict__ out_w, float* __restrict__ out) {
  __shared__ ushort_t s_ua[S_ * H_];       // 25.6 KB bf16
  __shared__ ushort_t s_M[768 * MROW];     // 81 KB f16, [j][54]
  __shared__ float s_res[NWROW];           // 4 KB
  __shared__ ushort_t s_hh[H_];            // f16 h (dot2 operand)
  __shared__ ushort_t s_wh[64];            // f16 attention weights
  __shared__ float s_va[H_];
  __shared__ float s_score[64];
  const int bidx = blockIdx.x, tid = threadIdx.x;

  if (bidx >= 32) {
    // ---- pack out_w into fragment-major g_wpk (bf16): p = (vt*32 + kg)*16 + c
    const size_t total = (size_t)VT_ * 32 * 16;
    for (size_t p = (size_t)(bidx - 32) * 1024 + tid; p < total;
         p += (size_t)(gridDim.x - 32) * 1024) {
      const int c = (int)(p & 15);
      const int kg = (int)((p >> 4) & 31);
      const int vt = (int)(p >> 9);
      const int v = vt * 16 + c;
      short8v val = {0, 0, 0, 0, 0, 0, 0, 0};
      if (v < V_) {
        const float4* owr = (const float4*)(out_w + (size_t)v * H_ + kg * 8);
        const float4 f0 = owr[0], f1 = owr[1];
        val[0] = (short)f2bf(f0.x); val[1] = (short)f2bf(f0.y);
        val[2] = (short)f2bf(f0.z); val[3] = (short)f2bf(f0.w);
        val[4] = (short)f2bf(f1.x); val[5] = (short)f2bf(f1.y);
        val[6] = (short)f2bf(f1.z); val[7] = (short)f2bf(f1.w);
      }
      ((short8v*)g_wpk)[p] = val;
    }
    return;
  }

  const int b = bidx;
  const int lane = tid & 63, wid = tid >> 6;
  const int sub = lane & 15;
  const int grp = tid >> 4;            // 0..63 row-slot (16 lanes per row)

  {
    const uint4* src = (const uint4*)(g_ua + (size_t)b * S_ * H_);
    uint4* dst = (uint4*)s_ua;
    for (int i = tid; i < S_ * H_ / 8; i += 1024) dst[i] = src[i];
    const uint4* src2 = (const uint4*)(g_MT2 + (size_t)b * 768 * MROW);
    uint4* dst2 = (uint4*)s_M;
    for (int i = tid; i < 768 * MROW / 8; i += 1024) dst2[i] = src2[i];
  }
  float hreg = 0.f, bhh0 = 0.f, bhh1 = 0.f, bhh2 = 0.f;
  if (tid < H_) {
    hreg = enc_h[b * H_ + tid];
    s_hh[tid] = f2h(hreg);
    s_va[tid] = Va_w[tid];
    bhh0 = b_hh[tid]; bhh1 = b_hh[H_ + tid]; bhh2 = b_hh[2 * H_ + tid];
  }
  const float vab = Va_b[0];
  __syncthreads();

  for (int t = 0; t < T_; ++t) {
    float gie0 = 0.f, gie1 = 0.f, gie2 = 0.f;
    if (tid < H_) {
      const float* gp = g_gie + ((size_t)t * B_ + b) * (3 * H_);
      gie0 = gp[tid]; gie1 = gp[H_ + tid]; gie2 = gp[2 * H_ + tid];
    }

    // ---- phase A: coalesced f16-dot2 sweep s_res[0..1024) = g_wcat . h
    {
      const unsigned int* hh = (const unsigned int*)s_hh;
#pragma unroll 4
      for (int it = 0; it < 16; ++it) {
        const int row = it * 64 + grp;
        const uint4* wr = (const uint4*)(g_wcat + (size_t)row * H_);
        const uint4 w0 = wr[sub], w1 = wr[16 + sub];
        float a = 0.f;
        a = dot2(w0.x, hh[sub * 4 + 0], a);
        a = dot2(w0.y, hh[sub * 4 + 1], a);
        a = dot2(w0.z, hh[sub * 4 + 2], a);
        a = dot2(w0.w, hh[sub * 4 + 3], a);
        a = dot2(w1.x, hh[64 + sub * 4 + 0], a);
        a = dot2(w1.y, hh[64 + sub * 4 + 1], a);
        a = dot2(w1.z, hh[64 + sub * 4 + 2], a);
        a = dot2(w1.w, hh[64 + sub * 4 + 3], a);
        a += __shfl_xor(a, 8); a += __shfl_xor(a, 4);
        a += __shfl_xor(a, 2); a += __shfl_xor(a, 1);
        if (sub == 0) s_res[row] = a;
      }
    }
    __syncthreads();

    // ---- phase B: scores
    for (int s = wid; s < S_; s += 16) {
      const ushort_t* uarow = s_ua + s * H_;
      float acc = 0.f;
#pragma unroll
      for (int i = 0; i < 4; ++i) {
        const int gg = lane + i * 64;
        acc += tanh_fast(s_res[gg] + bf2f(uarow[gg])) * s_va[gg];
      }
      for (int off = 32; off > 0; off >>= 1) acc += __shfl_xor(acc, off);
      if (lane == 0) s_score[s] = acc + vab;
    }
    __syncthreads();

    // ---- phase C: softmax on wave 0; write attention output
    if (tid < 64) {
      const float v = (tid < S_) ? s_score[tid] : -INFINITY;
      float m = v;
      for (int off = 32; off > 0; off >>= 1) m = fmaxf(m, __shfl_xor(m, off));
      const float e = (tid < S_) ? __expf(v - m) : 0.f;
      float ssum = e;
      for (int off = 32; off > 0; off >>= 1) ssum += __shfl_xor(ssum, off);
      const float w = e / ssum;
      if (tid < S_) {
        s_wh[tid] = f2h(w);
        out[(size_t)B_ * T_ * V_ + (size_t)B_ * H_ + (size_t)(b * T_ + t) * S_ + tid] = w;
      }
    }
    __syncthreads();

    // ---- phase D (fused): threads<256 compute 3x M.w dot2 chains + GRU + h update
    if (tid < H_) {
      const unsigned int* ww = (const unsigned int*)s_wh;
      const unsigned int* m0p = (const unsigned int*)s_M + tid * (MROW / 2);
      const unsigned int* m1p = (const unsigned int*)s_M + (H_ + tid) * (MROW / 2);
      const unsigned int* m2p = (const unsigned int*)s_M + (2 * H_ + tid) * (MROW / 2);
      float mw0 = 0.f, mw1 = 0.f, mw2 = 0.f;
#pragma unroll
      for (int i = 0; i < 25; ++i) {
        const unsigned int w = ww[i];
        mw0 = dot2(m0p[i], w, mw0);
        mw1 = dot2(m1p[i], w, mw1);
        mw2 = dot2(m2p[i], w, mw2);
      }
      const float gi0 = gie0 + mw0;
      const float gi1 = gie1 + mw1;
      const float gi2 = gie2 + mw2;
      const float gh0 = s_res[256 + tid] + bhh0;
      const float gh1 = s_res[512 + tid] + bhh1;
      const float gh2 = s_res[768 + tid] + bhh2;
      const float r = 1.f / (1.f + __expf(-(gi0 + gh0)));
      const float z = 1.f / (1.f + __expf(-(gi1 + gh1)));
      const float n = tanh_fast(gi2 + r * gh2);
      const float h2 = (1.f - z) * n + z * hreg;
      hreg = h2;
      s_hh[tid] = f2h(h2);
      g_hbf[((size_t)b * T_ + t) * H_ + tid] = f2bf(h2);
      if (t == T_ - 1) out[(size_t)B_ * T_ * V_ + b * H_ + tid] = h2;
    }
    __syncthreads();
  }
}

// ---------------- MFMA logits GEMM, B staged in LDS once, loop all 7 m-tiles.
// Pure GEMM + bf16 store (softmax sums moved to k_wlse).
__global__ void __launch_bounds__(512, 1)
k_logits(const float* __restrict__ out_b) {
  __shared__ ushort_t sA[128 * 256];   // 64 KB, XOR-swizzled rows
  __shared__ ushort_t sB[128 * 256];   // 64 KB, fragment-major copy of this block's B
  const int tid = threadIdx.x, nb = blockIdx.x;
  const int n0 = nb * 128;
  const int lane = tid & 63, wv = tid >> 6;
  const int wm = wv >> 1, wn = wv & 1;          // 4 x 2
  const int l16 = lane & 15, l4 = lane >> 4;

  {
    const short8v* src = (const short8v*)g_wpk + (size_t)nb * 4096;
    short8v* dst = (short8v*)sB;
    for (int i = tid; i < 4096; i += 512) dst[i] = src[i];
  }

  int vcol[4]; float bias[4]; bool valid[4];
#pragma unroll
  for (int ni = 0; ni < 4; ++ni) {
    vcol[ni] = n0 + wn * 64 + ni * 16 + l16;
    valid[ni] = (vcol[ni] < V_);
    bias[ni] = valid[ni] ? out_b[vcol[ni]] : 0.f;
  }

#pragma unroll 1
  for (int mt = 0; mt < 7; ++mt) {
    const int m0 = mt * 128;
    __syncthreads();
    for (int i = tid; i < 128 * 32; i += 512) {
      const int row = i >> 5, ks = i & 31;
      const int m = m0 + row;
      ushort8 val;
      if (m < NROW) val = ((const ushort8*)(g_hbf + (size_t)m * H_))[ks];
      else { ushort8 z = {0, 0, 0, 0, 0, 0, 0, 0}; val = z; }
      *(ushort8*)((char*)sA + row * 512 + ((ks ^ (row & 7)) << 4)) = val;
    }
    __syncthreads();

    f32x4 acc[2][4];
#pragma unroll
    for (int mi = 0; mi < 2; ++mi)
#pragma unroll
      for (int ni = 0; ni < 4; ++ni) acc[mi][ni] = (f32x4){0.f, 0.f, 0.f, 0.f};

#pragma unroll 1
    for (int kk = 0; kk < 8; ++kk) {
      short8v a[2], bfr[4];
#pragma unroll
      for (int mi = 0; mi < 2; ++mi) {
        const int row = wm * 32 + mi * 16 + l16;
        const int ks = kk * 4 + l4;
        a[mi] = *(const short8v*)((const char*)sA + row * 512 + ((ks ^ (row & 7)) << 4));
      }
#pragma unroll
      for (int ni = 0; ni < 4; ++ni)
        bfr[ni] = ((const short8v*)sB)[(((wn * 4 + ni) * 32) + kk * 4 + l4) * 16 + l16];
#pragma unroll
      for (int mi = 0; mi < 2; ++mi)
#pragma unroll
        for (int ni = 0; ni < 4; ++ni)
          acc[mi][ni] = __builtin_amdgcn_mfma_f32_16x16x32_bf16(a[mi], bfr[ni], acc[mi][ni], 0, 0, 0);
    }

#pragma unroll
    for (int mi = 0; mi < 2; ++mi) {
#pragma unroll
      for (int j = 0; j < 4; ++j) {
        const int m = m0 + wm * 32 + mi * 16 + l4 * 4 + j;
        if (m < NROW) {
#pragma unroll
          for (int ni = 0; ni < 4; ++ni)
            if (valid[ni]) g_lgt[(size_t)m * VP + vcol[ni]] = f2bf(acc[mi][ni][j] + bias[ni]);
        }
      }
    }
  }
}

// ---------------- lse from row scan (pass1) + write (pass2, L2-hot). grid 800 x 512
__global__ void k_wlse(float* __restrict__ out) {
  __shared__ float red[8];
  const int r = blockIdx.x;
  const int tid = threadIdx.x;
  const unsigned int* row32 = (const unsigned int*)(g_lgt + (size_t)r * VP);
  // pass 1: sum of exp over the row (fixed max 0; logits bounded ~|12|)
  float s = 0.f;
#pragma unroll 1
  for (int i = tid; i < V_ / 2; i += 512) {
    const unsigned int u = row32[i];
    s += __expf(bf2f((ushort_t)(u & 0xffffu)));
    s += __expf(bf2f((ushort_t)(u >> 16)));
  }
  if (tid == 0) s += __expf(bf2f(g_lgt[(size_t)r * VP + V_ - 1]));
  for (int off = 32; off > 0; off >>= 1) s += __shfl_xor(s, off);
  if ((tid & 63) == 0) red[tid >> 6] = s;
  __syncthreads();
  s = red[0] + red[1] + red[2] + red[3] + red[4] + red[5] + red[6] + red[7];
  float lse = logf(s);
  if (!isfinite(lse)) lse = 0.f;
  // pass 2: write (row L2-resident from pass 1)
  const size_t obase = (size_t)r * V_;
#pragma unroll 1
  for (int i = tid; i < V_ / 2; i += 512) {
    const unsigned int u = row32[i];
    out[obase + 2 * i]     = bf2f((ushort_t)(u & 0xffffu)) - lse;
    out[obase + 2 * i + 1] = bf2f((ushort_t)(u >> 16)) - lse;
  }
  if (tid == 0)
    out[obase + V_ - 1] = bf2f(g_lgt[(size_t)r * VP + V_ - 1]) - lse;
}

extern "C" void kernel_launch(void* const* d_in, const int* in_sizes, int n_in,
                              void* d_out, int out_size, void* d_ws, size_t ws_size,
                              hipStream_t stream) {
  const float* enc_h  = (const float*)d_in[0];
  const float* keys   = (const float*)d_in[1];
  const int*   tgt    = (const int*)d_in[2];
  const float* emb    = (const float*)d_in[3];
  const float* Wa_w   = (const float*)d_in[4];
  const float* Wa_b   = (const float*)d_in[5];
  const float* Ua_w   = (const float*)d_in[6];
  const float* Ua_b   = (const float*)d_in[7];
  const float* Va_w   = (const float*)d_in[8];
  const float* Va_b   = (const float*)d_in[9];
  const float* W_ih   = (const float*)d_in[10];
  const float* b_ih   = (const float*)d_in[11];
  const float* W_hh   = (const float*)d_in[12];
  const float* b_hh   = (const float*)d_in[13];
  const float* out_w  = (const float*)d_in[14];
  const float* out_b  = (const float*)d_in[15];
  float* out = (float*)d_out;
  (void)d_ws; (void)ws_size;

  hipLaunchKernelGGL(k_pre, dim3(966), dim3(256), 0, stream,
                     keys, Ua_w, Ua_b, Wa_b, W_hh, Wa_w, W_ih, b_ih, tgt, emb);
  hipLaunchKernelGGL(k_recur, dim3(32 + 1792), dim3(1024), 0, stream,
                     enc_h, Va_w, Va_b, b_hh, out_w, out);
  hipLaunchKernelGGL(k_logits, dim3(393), dim3(512), 0, stream, out_b);
  hipLaunchKernelGGL(k_wlse, dim3(NROW), dim3(512), 0, stream, out);
}

// Round 23
// 426.790 us; speedup vs baseline: 1.1690x; 1.0320x over previous
//
#include <hip/hip_runtime.h>
#include <math.h>

#define B_ 32
#define S_ 50
#define H_ 256
#define T_ 25
#define V_ 50257
#define VP 50264    /* padded g_lgt row: 16B-aligned (6283 uint4 groups) */
#define NROW (B_ * T_)
#define NWROW 1024  /* 256 Wa + 768 W_hh */
#define VT_ 3144    /* 393 * 8 vocab 16-col tiles */
#define MROW 54     /* padded M row (ushorts): 27 u32, gcd(27,32)=1 */
#define SOS 0

typedef unsigned short ushort_t;
typedef __attribute__((ext_vector_type(8))) unsigned short ushort8;
typedef __attribute__((ext_vector_type(8))) short short8v;
typedef __attribute__((ext_vector_type(4))) float f32x4;
typedef _Float16 half2v __attribute__((ext_vector_type(2)));

// ---- static device scratch (loader-allocated; fully rewritten each call)
__device__ ushort_t g_ua[B_ * S_ * H_];          // bf16 ua_keys + (Ua_b+Wa_b) folded
__device__ ushort_t g_hbf[NROW * H_];            // bf16 h2, row m = b*T+t
__device__ float    g_gie[T_ * B_ * 3 * H_];     // W_ih[:,:256].emb + b_ih
__device__ ushort_t g_wpk[(size_t)VT_ * 32 * 16 * 8];  // out_w bf16, fragment-major
__device__ ushort_t g_wcat[NWROW * H_];          // packed F16 [Wa; W_hh], K=256
__device__ ushort_t g_MT2[B_ * 768 * MROW];      // M[j][s] F16 padded rows
__device__ ushort_t g_lgt[(size_t)NROW * VP];    // bf16 logits staging (80 MB, padded)

__device__ __forceinline__ float bf2f(ushort_t h) {
  union { unsigned int u; float f; } c; c.u = ((unsigned int)h) << 16; return c.f;
}
__device__ __forceinline__ ushort_t f2bf(float f) {
  union { float f; unsigned int u; } c; c.f = f;
  unsigned int u = c.u;
  return (ushort_t)((u + 0x7FFFu + ((u >> 16) & 1u)) >> 16);
}
__device__ __forceinline__ ushort_t f2h(float f) {
  union { _Float16 h; ushort_t u; } c; c.h = (_Float16)f; return c.u;
}
__device__ __forceinline__ float dot2(unsigned int a, unsigned int b, float c) {
#if __has_builtin(__builtin_amdgcn_fdot2)
  union { unsigned int u; half2v h; } ca, cb;
  ca.u = a; cb.u = b;
  return __builtin_amdgcn_fdot2(ca.h, cb.h, c, false);
#else
  union { unsigned int u; _Float16 h[2]; } ca, cb;
  ca.u = a; cb.u = b;
  return c + (float)ca.h[0] * (float)cb.h[0] + (float)ca.h[1] * (float)cb.h[1];
#endif
}
__device__ __forceinline__ float tanh_fast(float x) {
  const float e = __expf(2.f * x);
  return 1.f - 2.f / (e + 1.f);
}

// ---------------- ONE setup launch, role by block range:
// [0,26): ua MFMA | [26,410): M | [410,710): gie | [710,966): wcat
__global__ void k_pre(const float* __restrict__ keys, const float* __restrict__ Ua_w,
                      const float* __restrict__ Ua_b, const float* __restrict__ Wa_b,
                      const float* __restrict__ W_hh, const float* __restrict__ Wa_w,
                      const float* __restrict__ W_ih, const float* __restrict__ b_ih,
                      const int* __restrict__ tgt, const float* __restrict__ emb_tab) {
  __shared__ float sbuf[16384];   // 64 KB, aliased per role
  const int bid = blockIdx.x, tid = threadIdx.x;

  if (bid < 26) {
    // ---- ua MFMA: ua[r=(b,s)][g] = keys_bf16[r,:] . Ua_w[g,:] + (Ua_b+Wa_b)[g]
    ushort_t* sA = (ushort_t*)sbuf;
    const int bx = bid & 1, by = bid >> 1;
    const int n0 = bx * 128, m0 = by * 128;
    const int lane = tid & 63, wv = tid >> 6;
    const int wm = wv >> 1, wn = wv & 1;
    const int l16 = lane & 15, l4 = lane >> 4;

    for (int i = tid; i < 128 * 32; i += 256) {
      const int row = i >> 5, ks = i & 31;
      const int m = m0 + row;
      ushort8 val = {0, 0, 0, 0, 0, 0, 0, 0};
      if (m < B_ * S_) {
        const float4* kr = (const float4*)(keys + (size_t)m * H_ + ks * 8);
        const float4 f0 = kr[0], f1 = kr[1];
        val[0] = f2bf(f0.x); val[1] = f2bf(f0.y); val[2] = f2bf(f0.z); val[3] = f2bf(f0.w);
        val[4] = f2bf(f1.x); val[5] = f2bf(f1.y); val[6] = f2bf(f1.z); val[7] = f2bf(f1.w);
      }
      *(ushort8*)((char*)sA + row * 512 + ((ks ^ (row & 7)) << 4)) = val;
    }
    __syncthreads();

    f32x4 acc[4][4];
#pragma unroll
    for (int mi = 0; mi < 4; ++mi)
#pragma unroll
      for (int ni = 0; ni < 4; ++ni) acc[mi][ni] = (f32x4){0.f, 0.f, 0.f, 0.f};

#pragma unroll 1
    for (int kk = 0; kk < 8; ++kk) {
      short8v a[4], bfr[4];
#pragma unroll
      for (int mi = 0; mi < 4; ++mi) {
        const int row = wm * 64 + mi * 16 + l16;
        const int ks = kk * 4 + l4;
        a[mi] = *(const short8v*)((const char*)sA + row * 512 + ((ks ^ (row & 7)) << 4));
      }
#pragma unroll
      for (int ni = 0; ni < 4; ++ni) {
        const int g = n0 + wn * 64 + ni * 16 + l16;
        const float4* wr = (const float4*)(Ua_w + (size_t)g * H_ + kk * 32 + l4 * 8);
        const float4 f0 = wr[0], f1 = wr[1];
        short8v bv;
        bv[0] = (short)f2bf(f0.x); bv[1] = (short)f2bf(f0.y);
        bv[2] = (short)f2bf(f0.z); bv[3] = (short)f2bf(f0.w);
        bv[4] = (short)f2bf(f1.x); bv[5] = (short)f2bf(f1.y);
        bv[6] = (short)f2bf(f1.z); bv[7] = (short)f2bf(f1.w);
        bfr[ni] = bv;
      }
#pragma unroll
      for (int mi = 0; mi < 4; ++mi)
#pragma unroll
        for (int ni = 0; ni < 4; ++ni)
          acc[mi][ni] = __builtin_amdgcn_mfma_f32_16x16x32_bf16(a[mi], bfr[ni], acc[mi][ni], 0, 0, 0);
    }

    int col[4]; float bias[4];
#pragma unroll
    for (int ni = 0; ni < 4; ++ni) {
      col[ni] = n0 + wn * 64 + ni * 16 + l16;
      bias[ni] = Ua_b[col[ni]] + Wa_b[col[ni]];
    }
#pragma unroll
    for (int mi = 0; mi < 4; ++mi) {
#pragma unroll
      for (int j = 0; j < 4; ++j) {
        const int m = m0 + wm * 64 + mi * 16 + l4 * 4 + j;
        if (m < B_ * S_) {
#pragma unroll
          for (int ni = 0; ni < 4; ++ni)
            g_ua[(size_t)m * H_ + col[ni]] = f2bf(acc[mi][ni][j] + bias[ni]);
        }
      }
    }
  } else if (bid < 410) {
    // ---- M[j][s] = W_ih[j,256:] . keys[b,s,:]  (F16 out)
    const int cc = bid - 26;
    const int c = cc % 12, b = cc / 12;
    {
      const float4* src = (const float4*)(keys + (size_t)b * S_ * H_);
      float4* dst = (float4*)sbuf;
      for (int i = tid; i < S_ * H_ / 4; i += 256) dst[i] = src[i];
    }
    __syncthreads();
    const int sub = tid & 15, grp = tid >> 4;
#pragma unroll 1
    for (int it = 0; it < 4; ++it) {
      const int j = c * 64 + it * 16 + grp;
      float w16[16];
#pragma unroll
      for (int kp = 0; kp < 16; ++kp)
        w16[kp] = W_ih[(size_t)j * (2 * H_) + H_ + sub + 16 * kp];
#pragma unroll 1
      for (int s = 0; s < S_; ++s) {
        float a = 0.f;
#pragma unroll
        for (int kp = 0; kp < 16; ++kp) a += w16[kp] * sbuf[s * H_ + sub + 16 * kp];
        a += __shfl_xor(a, 8); a += __shfl_xor(a, 4);
        a += __shfl_xor(a, 2); a += __shfl_xor(a, 1);
        if (sub == 0) g_MT2[(size_t)b * 768 * MROW + j * MROW + s] = f2h(a);
      }
    }
  } else if (bid < 710) {
    // ---- gie[t][b][j] = emb(tok[t,b]) . W_ih[j,:256] + b_ih[j]
    const int cc = bid - 410;
    const int chunk = cc % 12, t = cc / 12;
    for (int i = tid; i < B_ * H_; i += 256) {
      const int b = i >> 8, g = i & 255;
      const int tok = (t == 0) ? SOS : tgt[b * T_ + (t - 1)];
      sbuf[i] = emb_tab[(size_t)tok * H_ + g];
    }
    __syncthreads();
    const int vl = tid & 63, wd = tid >> 6;
    const int j = chunk * 64 + vl;
    const float4* wrow = (const float4*)(W_ih + (size_t)j * (2 * H_));
    const float4* se4 = (const float4*)sbuf;
    float acc[8];
    const float base = b_ih[j];
#pragma unroll
    for (int bb = 0; bb < 8; ++bb) acc[bb] = base;
    for (int k4 = 0; k4 < 64; ++k4) {
      const float4 w = wrow[k4];
#pragma unroll
      for (int bb = 0; bb < 8; ++bb) {
        const float4 x = se4[(wd * 8 + bb) * 64 + k4];
        acc[bb] += w.x * x.x + w.y * x.y + w.z * x.z + w.w * x.w;
      }
    }
#pragma unroll
    for (int bb = 0; bb < 8; ++bb)
      g_gie[((size_t)t * B_ + (wd * 8 + bb)) * (3 * H_) + j] = acc[bb];
  } else {
    // ---- wcat pack: [Wa; W_hh] -> F16
    const size_t i0 = (size_t)(bid - 710) * 256 + tid;
    for (size_t i = i0; i < (size_t)NWROW * H_; i += 256u * 256u) {
      const int r = (int)(i >> 8), k = (int)(i & 255);
      const float v = (r < 256) ? Wa_w[r * H_ + k] : W_hh[(r - 256) * H_ + k];
      g_wcat[i] = f2h(v);
    }
  }
}

// ---------------- recurrence (blocks 0..31) + g_wpk pack (blocks 32..) in ONE launch.
// Per step: [dot2 sweep | bar | scores | bar | softmax | bar | fused M.w+GRU | bar]
__global__ void __launch_bounds__(1024, 1)
k_recur(const float* __restrict__ enc_h, const float* __restrict__ Va_w,
        const float* __restrict__ Va_b, const float* __restrict__ b_hh,
        const float* __restrict__ out_w, float* __restrict__ out) {
  __shared__ ushort_t s_ua[S_ * H_];       // 25.6 KB bf16
  __shared__ ushort_t s_M[768 * MROW];     // 81 KB f16, [j][54]
  __shared__ float s_res[NWROW];           // 4 KB
  __shared__ ushort_t s_hh[H_];            // f16 h (dot2 operand)
  __shared__ ushort_t s_wh[64];            // f16 attention weights
  __shared__ float s_va[H_];
  __shared__ float s_score[64];
  const int bidx = blockIdx.x, tid = threadIdx.x;

  if (bidx >= 32) {
    // ---- pack out_w into fragment-major g_wpk (bf16): p = (vt*32 + kg)*16 + c
    const size_t total = (size_t)VT_ * 32 * 16;
    for (size_t p = (size_t)(bidx - 32) * 1024 + tid; p < total;
         p += (size_t)(gridDim.x - 32) * 1024) {
      const int c = (int)(p & 15);
      const int kg = (int)((p >> 4) & 31);
      const int vt = (int)(p >> 9);
      const int v = vt * 16 + c;
      short8v val = {0, 0, 0, 0, 0, 0, 0, 0};
      if (v < V_) {
        const float4* owr = (const float4*)(out_w + (size_t)v * H_ + kg * 8);
        const float4 f0 = owr[0], f1 = owr[1];
        val[0] = (short)f2bf(f0.x); val[1] = (short)f2bf(f0.y);
        val[2] = (short)f2bf(f0.z); val[3] = (short)f2bf(f0.w);
        val[4] = (short)f2bf(f1.x); val[5] = (short)f2bf(f1.y);
        val[6] = (short)f2bf(f1.z); val[7] = (short)f2bf(f1.w);
      }
      ((short8v*)g_wpk)[p] = val;
    }
    return;
  }

  const int b = bidx;
  const int lane = tid & 63, wid = tid >> 6;
  const int sub = lane & 15;
  const int grp = tid >> 4;            // 0..63 row-slot (16 lanes per row)

  {
    const uint4* src = (const uint4*)(g_ua + (size_t)b * S_ * H_);
    uint4* dst = (uint4*)s_ua;
    for (int i = tid; i < S_ * H_ / 8; i += 1024) dst[i] = src[i];
    const uint4* src2 = (const uint4*)(g_MT2 + (size_t)b * 768 * MROW);
    uint4* dst2 = (uint4*)s_M;
    for (int i = tid; i < 768 * MROW / 8; i += 1024) dst2[i] = src2[i];
  }
  float hreg = 0.f, bhh0 = 0.f, bhh1 = 0.f, bhh2 = 0.f;
  if (tid < H_) {
    hreg = enc_h[b * H_ + tid];
    s_hh[tid] = f2h(hreg);
    s_va[tid] = Va_w[tid];
    bhh0 = b_hh[tid]; bhh1 = b_hh[H_ + tid]; bhh2 = b_hh[2 * H_ + tid];
  }
  const float vab = Va_b[0];
  __syncthreads();

  for (int t = 0; t < T_; ++t) {
    float gie0 = 0.f, gie1 = 0.f, gie2 = 0.f;
    if (tid < H_) {
      const float* gp = g_gie + ((size_t)t * B_ + b) * (3 * H_);
      gie0 = gp[tid]; gie1 = gp[H_ + tid]; gie2 = gp[2 * H_ + tid];
    }

    // ---- phase A: coalesced f16-dot2 sweep s_res[0..1024) = g_wcat . h
    {
      const unsigned int* hh = (const unsigned int*)s_hh;
#pragma unroll 4
      for (int it = 0; it < 16; ++it) {
        const int row = it * 64 + grp;
        const uint4* wr = (const uint4*)(g_wcat + (size_t)row * H_);
        const uint4 w0 = wr[sub], w1 = wr[16 + sub];
        float a = 0.f;
        a = dot2(w0.x, hh[sub * 4 + 0], a);
        a = dot2(w0.y, hh[sub * 4 + 1], a);
        a = dot2(w0.z, hh[sub * 4 + 2], a);
        a = dot2(w0.w, hh[sub * 4 + 3], a);
        a = dot2(w1.x, hh[64 + sub * 4 + 0], a);
        a = dot2(w1.y, hh[64 + sub * 4 + 1], a);
        a = dot2(w1.z, hh[64 + sub * 4 + 2], a);
        a = dot2(w1.w, hh[64 + sub * 4 + 3], a);
        a += __shfl_xor(a, 8); a += __shfl_xor(a, 4);
        a += __shfl_xor(a, 2); a += __shfl_xor(a, 1);
        if (sub == 0) s_res[row] = a;
      }
    }
    __syncthreads();

    // ---- phase B: scores
    for (int s = wid; s < S_; s += 16) {
      const ushort_t* uarow = s_ua + s * H_;
      float acc = 0.f;
#pragma unroll
      for (int i = 0; i < 4; ++i) {
        const int gg = lane + i * 64;
        acc += tanh_fast(s_res[gg] + bf2f(uarow[gg])) * s_va[gg];
      }
      for (int off = 32; off > 0; off >>= 1) acc += __shfl_xor(acc, off);
      if (lane == 0) s_score[s] = acc + vab;
    }
    __syncthreads();

    // ---- phase C: softmax on wave 0; write attention output
    if (tid < 64) {
      const float v = (tid < S_) ? s_score[tid] : -INFINITY;
      float m = v;
      for (int off = 32; off > 0; off >>= 1) m = fmaxf(m, __shfl_xor(m, off));
      const float e = (tid < S_) ? __expf(v - m) : 0.f;
      float ssum = e;
      for (int off = 32; off > 0; off >>= 1) ssum += __shfl_xor(ssum, off);
      const float w = e / ssum;
      if (tid < S_) {
        s_wh[tid] = f2h(w);
        out[(size_t)B_ * T_ * V_ + (size_t)B_ * H_ + (size_t)(b * T_ + t) * S_ + tid] = w;
      }
    }
    __syncthreads();

    // ---- phase D (fused): threads<256 compute 3x M.w dot2 chains + GRU + h update
    if (tid < H_) {
      const unsigned int* ww = (const unsigned int*)s_wh;
      const unsigned int* m0p = (const unsigned int*)s_M + tid * (MROW / 2);
      const unsigned int* m1p = (const unsigned int*)s_M + (H_ + tid) * (MROW / 2);
      const unsigned int* m2p = (const unsigned int*)s_M + (2 * H_ + tid) * (MROW / 2);
      float mw0 = 0.f, mw1 = 0.f, mw2 = 0.f;
#pragma unroll
      for (int i = 0; i < 25; ++i) {
        const unsigned int w = ww[i];
        mw0 = dot2(m0p[i], w, mw0);
        mw1 = dot2(m1p[i], w, mw1);
        mw2 = dot2(m2p[i], w, mw2);
      }
      const float gi0 = gie0 + mw0;
      const float gi1 = gie1 + mw1;
      const float gi2 = gie2 + mw2;
      const float gh0 = s_res[256 + tid] + bhh0;
      const float gh1 = s_res[512 + tid] + bhh1;
      const float gh2 = s_res[768 + tid] + bhh2;
      const float r = 1.f / (1.f + __expf(-(gi0 + gh0)));
      const float z = 1.f / (1.f + __expf(-(gi1 + gh1)));
      const float n = tanh_fast(gi2 + r * gh2);
      const float h2 = (1.f - z) * n + z * hreg;
      hreg = h2;
      s_hh[tid] = f2h(h2);
      g_hbf[((size_t)b * T_ + t) * H_ + tid] = f2bf(h2);
      if (t == T_ - 1) out[(size_t)B_ * T_ * V_ + b * H_ + tid] = h2;
    }
    __syncthreads();
  }
}

// ---------------- MFMA logits GEMM, B staged in LDS once, loop all 7 m-tiles.
__global__ void __launch_bounds__(512, 1)
k_logits(const float* __restrict__ out_b) {
  __shared__ ushort_t sA[128 * 256];   // 64 KB, XOR-swizzled rows
  __shared__ ushort_t sB[128 * 256];   // 64 KB, fragment-major copy of this block's B
  const int tid = threadIdx.x, nb = blockIdx.x;
  const int n0 = nb * 128;
  const int lane = tid & 63, wv = tid >> 6;
  const int wm = wv >> 1, wn = wv & 1;          // 4 x 2
  const int l16 = lane & 15, l4 = lane >> 4;

  {
    const short8v* src = (const short8v*)g_wpk + (size_t)nb * 4096;
    short8v* dst = (short8v*)sB;
    for (int i = tid; i < 4096; i += 512) dst[i] = src[i];
  }

  int vcol[4]; float bias[4]; bool valid[4];
#pragma unroll
  for (int ni = 0; ni < 4; ++ni) {
    vcol[ni] = n0 + wn * 64 + ni * 16 + l16;
    valid[ni] = (vcol[ni] < V_);
    bias[ni] = valid[ni] ? out_b[vcol[ni]] : 0.f;
  }

#pragma unroll 1
  for (int mt = 0; mt < 7; ++mt) {
    const int m0 = mt * 128;
    __syncthreads();
    for (int i = tid; i < 128 * 32; i += 512) {
      const int row = i >> 5, ks = i & 31;
      const int m = m0 + row;
      ushort8 val;
      if (m < NROW) val = ((const ushort8*)(g_hbf + (size_t)m * H_))[ks];
      else { ushort8 z = {0, 0, 0, 0, 0, 0, 0, 0}; val = z; }
      *(ushort8*)((char*)sA + row * 512 + ((ks ^ (row & 7)) << 4)) = val;
    }
    __syncthreads();

    f32x4 acc[2][4];
#pragma unroll
    for (int mi = 0; mi < 2; ++mi)
#pragma unroll
      for (int ni = 0; ni < 4; ++ni) acc[mi][ni] = (f32x4){0.f, 0.f, 0.f, 0.f};

#pragma unroll 1
    for (int kk = 0; kk < 8; ++kk) {
      short8v a[2], bfr[4];
#pragma unroll
      for (int mi = 0; mi < 2; ++mi) {
        const int row = wm * 32 + mi * 16 + l16;
        const int ks = kk * 4 + l4;
        a[mi] = *(const short8v*)((const char*)sA + row * 512 + ((ks ^ (row & 7)) << 4));
      }
#pragma unroll
      for (int ni = 0; ni < 4; ++ni)
        bfr[ni] = ((const short8v*)sB)[(((wn * 4 + ni) * 32) + kk * 4 + l4) * 16 + l16];
#pragma unroll
      for (int mi = 0; mi < 2; ++mi)
#pragma unroll
        for (int ni = 0; ni < 4; ++ni)
          acc[mi][ni] = __builtin_amdgcn_mfma_f32_16x16x32_bf16(a[mi], bfr[ni], acc[mi][ni], 0, 0, 0);
    }

#pragma unroll
    for (int mi = 0; mi < 2; ++mi) {
#pragma unroll
      for (int j = 0; j < 4; ++j) {
        const int m = m0 + wm * 32 + mi * 16 + l4 * 4 + j;
        if (m < NROW) {
#pragma unroll
          for (int ni = 0; ni < 4; ++ni)
            if (valid[ni]) g_lgt[(size_t)m * VP + vcol[ni]] = f2bf(acc[mi][ni][j] + bias[ni]);
        }
      }
    }
  }
}

// ---------------- lse from row scan (pass1, uint4) + write (pass2, uint4, L2-hot). grid 800 x 512
__global__ void k_wlse(float* __restrict__ out) {
  __shared__ float red[8];
  const int r = blockIdx.x;
  const int tid = threadIdx.x;
  const uint4* row16 = (const uint4*)(g_lgt + (size_t)r * VP);
  // pass 1: sum of exp over the row (fixed max 0; logits bounded ~|12|).
  // groups 0..6282 cover V_ + 7 pad lanes (never written, .bss zeros -> exp(0)=1 each;
  // +7 on a sum of ~5e4 shifts lse by ~1e-4: negligible and deterministic). Compensate
  // exactly by subtracting 7 before the log.
  float s = 0.f;
#pragma unroll 1
  for (int g = tid; g < 6283; g += 512) {
    const uint4 u = row16[g];
    s += __expf(bf2f((ushort_t)(u.x & 0xffffu))) + __expf(bf2f((ushort_t)(u.x >> 16)));
    s += __expf(bf2f((ushort_t)(u.y & 0xffffu))) + __expf(bf2f((ushort_t)(u.y >> 16)));
    s += __expf(bf2f((ushort_t)(u.z & 0xffffu))) + __expf(bf2f((ushort_t)(u.z >> 16)));
    s += __expf(bf2f((ushort_t)(u.w & 0xffffu))) + __expf(bf2f((ushort_t)(u.w >> 16)));
  }
  for (int off = 32; off > 0; off >>= 1) s += __shfl_xor(s, off);
  if ((tid & 63) == 0) red[tid >> 6] = s;
  __syncthreads();
  s = red[0] + red[1] + red[2] + red[3] + red[4] + red[5] + red[6] + red[7];
  s -= 7.f * __expf(0.f);   // exact pad compensation (pads are bf16 zero)
  float lse = logf(s);
  if (!isfinite(lse)) lse = 0.f;
  // pass 2: write (row L2-resident from pass 1); groups 0..6281 full, tail group 1 elem
  const size_t obase = (size_t)r * V_;
#pragma unroll 1
  for (int g = tid; g < 6282; g += 512) {
    const uint4 u = row16[g];
    const size_t o = obase + (size_t)g * 8;
    out[o + 0] = bf2f((ushort_t)(u.x & 0xffffu)) - lse;
    out[o + 1] = bf2f((ushort_t)(u.x >> 16)) - lse;
    out[o + 2] = bf2f((ushort_t)(u.y & 0xffffu)) - lse;
    out[o + 3] = bf2f((ushort_t)(u.y >> 16)) - lse;
    out[o + 4] = bf2f((ushort_t)(u.z & 0xffffu)) - lse;
    out[o + 5] = bf2f((ushort_t)(u.z >> 16)) - lse;
    out[o + 6] = bf2f((ushort_t)(u.w & 0xffffu)) - lse;
    out[o + 7] = bf2f((ushort_t)(u.w >> 16)) - lse;
  }
  if (tid == 0)
    out[obase + V_ - 1] = bf2f(g_lgt[(size_t)r * VP + V_ - 1]) - lse;
}

extern "C" void kernel_launch(void* const* d_in, const int* in_sizes, int n_in,
                              void* d_out, int out_size, void* d_ws, size_t ws_size,
                              hipStream_t stream) {
  const float* enc_h  = (const float*)d_in[0];
  const float* keys   = (const float*)d_in[1];
  const int*   tgt    = (const int*)d_in[2];
  const float* emb    = (const float*)d_in[3];
  const float* Wa_w   = (const float*)d_in[4];
  const float* Wa_b   = (const float*)d_in[5];
  const float* Ua_w   = (const float*)d_in[6];
  const float* Ua_b   = (const float*)d_in[7];
  const float* Va_w   = (const float*)d_in[8];
  const float* Va_b   = (const float*)d_in[9];
  const float* W_ih   = (const float*)d_in[10];
  const float* b_ih   = (const float*)d_in[11];
  const float* W_hh   = (const float*)d_in[12];
  const float* b_hh   = (const float*)d_in[13];
  const float* out_w  = (const float*)d_in[14];
  const float* out_b  = (const float*)d_in[15];
  float* out = (float*)d_out;
  (void)d_ws; (void)ws_size;

  hipLaunchKernelGGL(k_pre, dim3(966), dim3(256), 0, stream,
                     keys, Ua_w, Ua_b, Wa_b, W_hh, Wa_w, W_ih, b_ih, tgt, emb);
  hipLaunchKernelGGL(k_recur, dim3(32 + 1792), dim3(1024), 0, stream,
                     enc_h, Va_w, Va_b, b_hh, out_w, out);
  hipLaunchKernelGGL(k_logits, dim3(393), dim3(512), 0, stream, out_b);
  hipLaunchKernelGGL(k_wlse, dim3(NROW), dim3(512), 0, stream, out);
}